// Round 1
// baseline (1018.148 us; speedup 1.0000x reference)
//
#include <hip/hip_runtime.h>
#include <hip/hip_bf16.h>
#include <math.h>

#define N_NODES   50000
#define N_EDGES   800000
#define N_GRAPHS  64
#define IN_CH     128
#define GLOBAL_DIM 256
#define HIDDEN    64
#define HEADS     4
#define N_CLASSES 10
#define QKV_COLS  832   // 256 q | 256 k | 256 v | 64 skip

// ---------------------------------------------------------------------------
// CSR build: deg -> inclusive scan -> rowptr/cursor -> fill col (src ids)
// ---------------------------------------------------------------------------
__global__ void count_deg(const int* __restrict__ dst, int* __restrict__ deg) {
    int e = blockIdx.x * 256 + threadIdx.x;
    if (e < N_EDGES) atomicAdd(&deg[dst[e]], 1);
}

__global__ void scan1(const int* __restrict__ deg, int* __restrict__ incl,
                      int* __restrict__ bsums, int n) {
    __shared__ int sh[1024];
    int t = threadIdx.x;
    int gid = blockIdx.x * 1024 + t;
    int v = (gid < n) ? deg[gid] : 0;
    sh[t] = v;
    __syncthreads();
    for (int off = 1; off < 1024; off <<= 1) {
        int tmp = (t >= off) ? sh[t - off] : 0;
        __syncthreads();
        sh[t] += tmp;
        __syncthreads();
    }
    if (gid < n) incl[gid] = sh[t];
    if (t == 1023) bsums[blockIdx.x] = sh[1023];
}

__global__ void scan2(const int* __restrict__ bsums, int* __restrict__ boff, int nb) {
    if (blockIdx.x == 0 && threadIdx.x == 0) {
        int acc = 0;
        for (int i = 0; i < nb; ++i) { boff[i] = acc; acc += bsums[i]; }
    }
}

__global__ void scan3(const int* __restrict__ deg, const int* __restrict__ incl,
                      const int* __restrict__ boff, int* __restrict__ rowptr,
                      int* __restrict__ cur, int n) {
    int gid = blockIdx.x * 256 + threadIdx.x;
    if (gid < n) {
        int b = gid >> 10;
        int in = incl[gid] + boff[b];
        int ex = in - deg[gid];
        rowptr[gid] = ex;
        cur[gid] = ex;
        if (gid == n - 1) rowptr[n] = in;
    }
}

__global__ void fill_col(const int* __restrict__ src, const int* __restrict__ dst,
                         int* __restrict__ cur, int* __restrict__ col) {
    int e = blockIdx.x * 256 + threadIdx.x;
    if (e < N_EDGES) {
        int d = dst[e];
        int pos = atomicAdd(&cur[d], 1);
        col[pos] = src[e];
    }
}

// ---------------------------------------------------------------------------
// Concatenate Wq|Wk|Wv|Ws -> Wcat [K,832], biases -> bcat[832]
// ---------------------------------------------------------------------------
__global__ void concat_w(const float* __restrict__ Wq, const float* __restrict__ Wk,
                         const float* __restrict__ Wv, const float* __restrict__ Ws,
                         const float* __restrict__ bq, const float* __restrict__ bk,
                         const float* __restrict__ bv, const float* __restrict__ bs,
                         float* __restrict__ Wcat, float* __restrict__ bcat, int K) {
    int idx = blockIdx.x * 256 + threadIdx.x;
    int total = K * QKV_COLS;
    if (idx < total) {
        int k = idx / QKV_COLS, c = idx % QKV_COLS;
        float v;
        if (c < 256)      v = Wq[k * 256 + c];
        else if (c < 512) v = Wk[k * 256 + (c - 256)];
        else if (c < 768) v = Wv[k * 256 + (c - 512)];
        else              v = Ws[k * 64  + (c - 768)];
        Wcat[idx] = v;
    }
    if (idx < QKV_COLS) {
        float b;
        if (idx < 256)      b = bq[idx];
        else if (idx < 512) b = bk[idx - 256];
        else if (idx < 768) b = bv[idx - 512];
        else                b = bs[idx - 768];
        bcat[idx] = b;
    }
}

// ---------------------------------------------------------------------------
// Tiled fp32 GEMM: C[N x 832] = A[N x K] @ W[K x 832] + bias, 64x64 tiles
// ---------------------------------------------------------------------------
template <int K>
__global__ __launch_bounds__(256) void gemm_tile(const float* __restrict__ A,
                                                 const float* __restrict__ W,
                                                 const float* __restrict__ bias,
                                                 float* __restrict__ C, int N) {
    constexpr int Kq = K / 4;
    __shared__ float At[K * 68];   // At[k][r], stride 68 breaks bank aliasing
    __shared__ float Bt[K * 68];   // Bt[k][c]
    const int t = threadIdx.x;
    const int base_r = blockIdx.x * 64;
    const int base_c = blockIdx.y * 64;

    // stage A (transposed) -- fully coalesced float4 reads
#pragma unroll
    for (int i = 0; i < (64 * Kq) / 256; ++i) {
        int idx = t + i * 256;
        int r = idx / Kq, kq = idx % Kq;
        float4 av = make_float4(0.f, 0.f, 0.f, 0.f);
        int gr = base_r + r;
        if (gr < N) av = *(const float4*)(A + (size_t)gr * K + kq * 4);
        At[(kq * 4 + 0) * 68 + r] = av.x;
        At[(kq * 4 + 1) * 68 + r] = av.y;
        At[(kq * 4 + 2) * 68 + r] = av.z;
        At[(kq * 4 + 3) * 68 + r] = av.w;
    }
    // stage B
#pragma unroll
    for (int i = 0; i < (K * 16) / 256; ++i) {
        int idx = t + i * 256;
        int k = idx / 16, c4 = idx % 16;
        float4 bv = *(const float4*)(W + (size_t)k * QKV_COLS + base_c + c4 * 4);
        *(float4*)(Bt + k * 68 + c4 * 4) = bv;
    }
    __syncthreads();

    const int tx = t & 15, ty = t >> 4;
    float acc[4][4];
#pragma unroll
    for (int i = 0; i < 4; ++i)
#pragma unroll
        for (int j = 0; j < 4; ++j) acc[i][j] = 0.f;

#pragma unroll 4
    for (int kk = 0; kk < K; ++kk) {
        float4 b = *(const float4*)(Bt + kk * 68 + tx * 4);
        float a0 = At[kk * 68 + ty * 4 + 0];
        float a1 = At[kk * 68 + ty * 4 + 1];
        float a2 = At[kk * 68 + ty * 4 + 2];
        float a3 = At[kk * 68 + ty * 4 + 3];
        acc[0][0] = fmaf(a0, b.x, acc[0][0]); acc[0][1] = fmaf(a0, b.y, acc[0][1]);
        acc[0][2] = fmaf(a0, b.z, acc[0][2]); acc[0][3] = fmaf(a0, b.w, acc[0][3]);
        acc[1][0] = fmaf(a1, b.x, acc[1][0]); acc[1][1] = fmaf(a1, b.y, acc[1][1]);
        acc[1][2] = fmaf(a1, b.z, acc[1][2]); acc[1][3] = fmaf(a1, b.w, acc[1][3]);
        acc[2][0] = fmaf(a2, b.x, acc[2][0]); acc[2][1] = fmaf(a2, b.y, acc[2][1]);
        acc[2][2] = fmaf(a2, b.z, acc[2][2]); acc[2][3] = fmaf(a2, b.w, acc[2][3]);
        acc[3][0] = fmaf(a3, b.x, acc[3][0]); acc[3][1] = fmaf(a3, b.y, acc[3][1]);
        acc[3][2] = fmaf(a3, b.z, acc[3][2]); acc[3][3] = fmaf(a3, b.w, acc[3][3]);
    }

    float4 bv4 = *(const float4*)(bias + base_c + tx * 4);
#pragma unroll
    for (int i = 0; i < 4; ++i) {
        int r = base_r + ty * 4 + i;
        if (r < N) {
            float4 o;
            o.x = acc[i][0] + bv4.x; o.y = acc[i][1] + bv4.y;
            o.z = acc[i][2] + bv4.z; o.w = acc[i][3] + bv4.w;
            *(float4*)(C + (size_t)r * QKV_COLS + base_c + tx * 4) = o;
        }
    }
}

// ---------------------------------------------------------------------------
// TransformerConv aggregation: one wave per dst node.
// lane holds dims [4*lane, 4*lane+4) of the 256-dim q/k/v; head = lane>>4.
// out = relu( mean_h( sum_e softmax(qk/8) * v ) + skip ), bias already in skip.
// ---------------------------------------------------------------------------
__global__ __launch_bounds__(256) void attn_agg(const float* __restrict__ qkv,
                                                const int* __restrict__ rowptr,
                                                const int* __restrict__ col,
                                                float* __restrict__ hout) {
    int node = blockIdx.x * 4 + threadIdx.y;
    if (node >= N_NODES) return;
    int lane = threadIdx.x;
    const float* row = qkv + (size_t)node * QKV_COLS;
    float4 q = *(const float4*)(row + lane * 4);
    float ax = 0.f, ay = 0.f, az = 0.f, aw = 0.f, z = 0.f;
    int beg = rowptr[node], end = rowptr[node + 1];
    for (int e = beg; e < end; ++e) {
        int s = col[e];
        const float* srow = qkv + (size_t)s * QKV_COLS;
        float4 kv = *(const float4*)(srow + 256 + lane * 4);
        float4 vv = *(const float4*)(srow + 512 + lane * 4);
        float d = q.x * kv.x + q.y * kv.y + q.z * kv.z + q.w * kv.w;
        d += __shfl_xor(d, 1);
        d += __shfl_xor(d, 2);
        d += __shfl_xor(d, 4);
        d += __shfl_xor(d, 8);
        float p = __expf(d * 0.125f);   // s/sqrt(64); |s|<1 so no max-shift needed
        z += p;
        ax = fmaf(p, vv.x, ax); ay = fmaf(p, vv.y, ay);
        az = fmaf(p, vv.z, az); aw = fmaf(p, vv.w, aw);
    }
    float inv = (z > 0.f) ? (1.f / z) : 0.f;
    ax *= inv; ay *= inv; az *= inv; aw *= inv;
    // mean over heads: lanes l, l+16, l+32, l+48 hold the same local dim
    ax += __shfl_xor(ax, 16); ax += __shfl_xor(ax, 32);
    ay += __shfl_xor(ay, 16); ay += __shfl_xor(ay, 32);
    az += __shfl_xor(az, 16); az += __shfl_xor(az, 32);
    aw += __shfl_xor(aw, 16); aw += __shfl_xor(aw, 32);
    if (lane < 16) {
        float4 sk = *(const float4*)(row + 768 + lane * 4);
        float4 o;
        o.x = fmaxf(ax * 0.25f + sk.x, 0.f);
        o.y = fmaxf(ay * 0.25f + sk.y, 0.f);
        o.z = fmaxf(az * 0.25f + sk.z, 0.f);
        o.w = fmaxf(aw * 0.25f + sk.w, 0.f);
        *(float4*)(hout + (size_t)node * HIDDEN + lane * 4) = o;
    }
}

// ---------------------------------------------------------------------------
// Per-graph mean pool (batch is sorted -> binary search boundaries, no atomics)
// ---------------------------------------------------------------------------
__global__ void pool_mean(const float* __restrict__ h, const int* __restrict__ batch,
                          float* __restrict__ gsum, int* __restrict__ gcnt) {
    int g = blockIdx.x;
    int lo = 0, hi = N_NODES;
    while (lo < hi) { int mid = (lo + hi) >> 1; if (batch[mid] < g) lo = mid + 1; else hi = mid; }
    int start = lo;
    hi = N_NODES;
    while (lo < hi) { int mid = (lo + hi) >> 1; if (batch[mid] < g + 1) lo = mid + 1; else hi = mid; }
    int end = lo;
    int t = threadIdx.x;
    int d = t & 63, chunk = t >> 6;   // 256 threads: 4 chunks x 64 dims
    float acc = 0.f;
    for (int n = start + chunk; n < end; n += 4) acc += h[(size_t)n * HIDDEN + d];
    __shared__ float sh[256];
    sh[t] = acc;
    __syncthreads();
    if (chunk == 0) {
        gsum[g * HIDDEN + d] = sh[d] + sh[64 + d] + sh[128 + d] + sh[192 + d];
        if (d == 0) gcnt[g] = end - start;
    }
}

// ---------------------------------------------------------------------------
// Final MLP head: one block (64 threads) per graph
// ---------------------------------------------------------------------------
__global__ __launch_bounds__(64) void mlp_head(const float* __restrict__ gsum,
                                               const int* __restrict__ gcnt,
                                               const float* __restrict__ gf,
                                               const float* __restrict__ gW1, const float* __restrict__ gb1,
                                               const float* __restrict__ gW2, const float* __restrict__ gb2,
                                               const float* __restrict__ hW1, const float* __restrict__ hb1,
                                               const float* __restrict__ hW2, const float* __restrict__ hb2,
                                               float* __restrict__ out) {
    int g = blockIdx.x;
    int t = threadIdx.x;   // 64 threads
    __shared__ float gfs[GLOBAL_DIM];
    __shared__ float g1[HIDDEN];
    __shared__ float fused[2 * HIDDEN];
    __shared__ float h1s[HIDDEN];
    for (int i = t; i < GLOBAL_DIM; i += 64) gfs[i] = gf[(size_t)g * GLOBAL_DIM + i];
    float cnt = (float)gcnt[g];
    cnt = fmaxf(cnt, 1.0f);
    fused[t] = gsum[g * HIDDEN + t] / cnt;   // patch_emb
    __syncthreads();
    float acc = gb1[t];
    for (int k = 0; k < GLOBAL_DIM; ++k) acc = fmaf(gfs[k], gW1[k * HIDDEN + t], acc);
    g1[t] = fmaxf(acc, 0.f);
    __syncthreads();
    acc = gb2[t];
    for (int k = 0; k < HIDDEN; ++k) acc = fmaf(g1[k], gW2[k * HIDDEN + t], acc);
    fused[HIDDEN + t] = fmaxf(acc, 0.f);
    __syncthreads();
    acc = hb1[t];
    for (int k = 0; k < 2 * HIDDEN; ++k) acc = fmaf(fused[k], hW1[k * HIDDEN + t], acc);
    h1s[t] = fmaxf(acc, 0.f);
    __syncthreads();
    if (t < N_CLASSES) {
        float o = hb2[t];
        for (int k = 0; k < HIDDEN; ++k) o = fmaf(h1s[k], hW2[k * N_CLASSES + t], o);
        out[(size_t)g * N_CLASSES + t] = o;
    }
}

// ---------------------------------------------------------------------------
extern "C" void kernel_launch(void* const* d_in, const int* in_sizes, int n_in,
                              void* d_out, int out_size, void* d_ws, size_t ws_size,
                              hipStream_t stream) {
    const float* x        = (const float*)d_in[0];
    const int*   eidx     = (const int*)d_in[1];
    const int*   batch    = (const int*)d_in[2];
    const float* gfeats   = (const float*)d_in[3];
    const float* c1_Wq = (const float*)d_in[4];  const float* c1_bq = (const float*)d_in[5];
    const float* c1_Wk = (const float*)d_in[6];  const float* c1_bk = (const float*)d_in[7];
    const float* c1_Wv = (const float*)d_in[8];  const float* c1_bv = (const float*)d_in[9];
    const float* c1_Ws = (const float*)d_in[10]; const float* c1_bs = (const float*)d_in[11];
    const float* c2_Wq = (const float*)d_in[12]; const float* c2_bq = (const float*)d_in[13];
    const float* c2_Wk = (const float*)d_in[14]; const float* c2_bk = (const float*)d_in[15];
    const float* c2_Wv = (const float*)d_in[16]; const float* c2_bv = (const float*)d_in[17];
    const float* c2_Ws = (const float*)d_in[18]; const float* c2_bs = (const float*)d_in[19];
    const float* g_W1 = (const float*)d_in[20]; const float* g_b1 = (const float*)d_in[21];
    const float* g_W2 = (const float*)d_in[22]; const float* g_b2 = (const float*)d_in[23];
    const float* h_W1 = (const float*)d_in[24]; const float* h_b1 = (const float*)d_in[25];
    const float* h_W2 = (const float*)d_in[26]; const float* h_b2 = (const float*)d_in[27];
    float* out = (float*)d_out;

    const int* srcp = eidx;
    const int* dstp = eidx + N_EDGES;

    // ---- workspace layout (floats first, then ints), all 16B aligned ----
    float* ws = (float*)d_ws;
    size_t o = 0;
    float* qkv  = ws + o; o += (size_t)N_NODES * QKV_COLS;   // 41,600,000
    float* h1   = ws + o; o += (size_t)N_NODES * HIDDEN;     //  3,200,000
    float* h2   = ws + o; o += (size_t)N_NODES * HIDDEN;
    float* Wcat = ws + o; o += (size_t)IN_CH * QKV_COLS;     // 106,496 (max K)
    float* bcat = ws + o; o += QKV_COLS;
    float* gsum = ws + o; o += N_GRAPHS * HIDDEN;
    int* ib = (int*)(ws + o);
    size_t oi = 0;
    int* deg    = ib + oi; oi += N_NODES;
    int* incl   = ib + oi; oi += N_NODES;
    int* bsums  = ib + oi; oi += 64;
    int* boff   = ib + oi; oi += 64;
    int* rowptr = ib + oi; oi += N_NODES + 4;
    int* cur    = ib + oi; oi += N_NODES;
    int* colb   = ib + oi; oi += N_EDGES;
    int* gcnt   = ib + oi; oi += 64;

    const int NB1 = (N_NODES + 1023) / 1024;   // 49
    const int EB  = (N_EDGES + 255) / 256;     // 3125
    const int NBS = (N_NODES + 255) / 256;     // 196

    // ---- CSR build (shared by both conv layers) ----
    hipMemsetAsync(deg, 0, N_NODES * sizeof(int), stream);
    count_deg<<<EB, 256, 0, stream>>>(dstp, deg);
    scan1<<<NB1, 1024, 0, stream>>>(deg, incl, bsums, N_NODES);
    scan2<<<1, 64, 0, stream>>>(bsums, boff, NB1);
    scan3<<<NBS, 256, 0, stream>>>(deg, incl, boff, rowptr, cur, N_NODES);
    fill_col<<<EB, 256, 0, stream>>>(srcp, dstp, cur, colb);

    dim3 gemm_grid((N_NODES + 63) / 64, QKV_COLS / 64);   // 782 x 13
    dim3 attn_block(64, 4);
    int attn_grid = (N_NODES + 3) / 4;                    // 12500

    // ---- conv1 ----
    concat_w<<<(IN_CH * QKV_COLS + 255) / 256, 256, 0, stream>>>(
        c1_Wq, c1_Wk, c1_Wv, c1_Ws, c1_bq, c1_bk, c1_bv, c1_bs, Wcat, bcat, IN_CH);
    gemm_tile<IN_CH><<<gemm_grid, 256, 0, stream>>>(x, Wcat, bcat, qkv, N_NODES);
    attn_agg<<<attn_grid, attn_block, 0, stream>>>(qkv, rowptr, colb, h1);

    // ---- conv2 (reuses qkv buffer) ----
    concat_w<<<(HIDDEN * QKV_COLS + 255) / 256, 256, 0, stream>>>(
        c2_Wq, c2_Wk, c2_Wv, c2_Ws, c2_bq, c2_bk, c2_bv, c2_bs, Wcat, bcat, HIDDEN);
    gemm_tile<HIDDEN><<<gemm_grid, 256, 0, stream>>>(h1, Wcat, bcat, qkv, N_NODES);
    attn_agg<<<attn_grid, attn_block, 0, stream>>>(qkv, rowptr, colb, h2);

    // ---- pool + head ----
    pool_mean<<<N_GRAPHS, 256, 0, stream>>>(h2, batch, gsum, gcnt);
    mlp_head<<<N_GRAPHS, 64, 0, stream>>>(gsum, gcnt, gfeats,
                                          g_W1, g_b1, g_W2, g_b2,
                                          h_W1, h_b1, h_W2, h_b2, out);
}

// Round 2
// 676.862 us; speedup vs baseline: 1.5042x; 1.5042x over previous
//
#include <hip/hip_runtime.h>
#include <hip/hip_bf16.h>
#include <math.h>

#define N_NODES   50000
#define N_EDGES   800000
#define N_GRAPHS  64
#define IN_CH     128
#define GLOBAL_DIM 256
#define HIDDEN    64
#define HEADS     4
#define N_CLASSES 10
#define QKV_COLS  832   // 256 q | 256 k | 256 v | 64 skip
#define QKV_B     768   // bf16 part (q|k|v)

typedef unsigned short ushort_t;
typedef unsigned int uint_t;
typedef __attribute__((ext_vector_type(8))) short short8;
typedef __attribute__((ext_vector_type(4))) float floatx4;

// ---------------------------------------------------------------------------
// helpers: bf16 <-> fp32 bit tricks (RNE for the cast down)
// ---------------------------------------------------------------------------
__device__ __forceinline__ ushort_t bf16rne(float f) {
    uint_t b = __float_as_uint(f);
    b += 0x7fffu + ((b >> 16) & 1u);
    return (ushort_t)(b >> 16);
}
__device__ __forceinline__ float4 bf4_unpack(uint2 u) {
    float4 f;
    f.x = __uint_as_float(u.x << 16);
    f.y = __uint_as_float(u.x & 0xffff0000u);
    f.z = __uint_as_float(u.y << 16);
    f.w = __uint_as_float(u.y & 0xffff0000u);
    return f;
}

// ---------------------------------------------------------------------------
// CSR build: deg -> inclusive scan -> rowptr/cursor -> fill col (src ids)
// ---------------------------------------------------------------------------
__global__ void count_deg(const int* __restrict__ dst, int* __restrict__ deg) {
    int e = blockIdx.x * 256 + threadIdx.x;
    if (e < N_EDGES) atomicAdd(&deg[dst[e]], 1);
}

__global__ void scan1(const int* __restrict__ deg, int* __restrict__ incl,
                      int* __restrict__ bsums, int n) {
    __shared__ int sh[1024];
    int t = threadIdx.x;
    int gid = blockIdx.x * 1024 + t;
    int v = (gid < n) ? deg[gid] : 0;
    sh[t] = v;
    __syncthreads();
    for (int off = 1; off < 1024; off <<= 1) {
        int tmp = (t >= off) ? sh[t - off] : 0;
        __syncthreads();
        sh[t] += tmp;
        __syncthreads();
    }
    if (gid < n) incl[gid] = sh[t];
    if (t == 1023) bsums[blockIdx.x] = sh[1023];
}

__global__ void scan2(const int* __restrict__ bsums, int* __restrict__ boff, int nb) {
    if (blockIdx.x == 0 && threadIdx.x == 0) {
        int acc = 0;
        for (int i = 0; i < nb; ++i) { boff[i] = acc; acc += bsums[i]; }
    }
}

__global__ void scan3(const int* __restrict__ deg, const int* __restrict__ incl,
                      const int* __restrict__ boff, int* __restrict__ rowptr,
                      int* __restrict__ cur, int n) {
    int gid = blockIdx.x * 256 + threadIdx.x;
    if (gid < n) {
        int b = gid >> 10;
        int in = incl[gid] + boff[b];
        int ex = in - deg[gid];
        rowptr[gid] = ex;
        cur[gid] = ex;
        if (gid == n - 1) rowptr[n] = in;
    }
}

__global__ void fill_col(const int* __restrict__ src, const int* __restrict__ dst,
                         int* __restrict__ cur, int* __restrict__ col) {
    int e = blockIdx.x * 256 + threadIdx.x;
    if (e < N_EDGES) {
        int d = dst[e];
        int pos = atomicAdd(&cur[d], 1);
        col[pos] = src[e];
    }
}

// ---------------------------------------------------------------------------
// cast fp32 -> bf16, 8 elems/thread
// ---------------------------------------------------------------------------
__global__ void cast_bf16_x8(const float* __restrict__ in, ushort_t* __restrict__ out, int n8) {
    int idx = blockIdx.x * 256 + threadIdx.x;
    if (idx >= n8) return;
    size_t i = (size_t)idx * 8;
    float4 a = *(const float4*)(in + i);
    float4 b = *(const float4*)(in + i + 4);
    uint4 u;
    u.x = (uint_t)bf16rne(a.x) | ((uint_t)bf16rne(a.y) << 16);
    u.y = (uint_t)bf16rne(a.z) | ((uint_t)bf16rne(a.w) << 16);
    u.z = (uint_t)bf16rne(b.x) | ((uint_t)bf16rne(b.y) << 16);
    u.w = (uint_t)bf16rne(b.z) | ((uint_t)bf16rne(b.w) << 16);
    *(uint4*)(out + i) = u;
}

// ---------------------------------------------------------------------------
// Concatenate + transpose weights: Wt[c][k] (bf16), c in [0,832), plus bcat fp32
// ---------------------------------------------------------------------------
__global__ void concat_w_t(const float* __restrict__ Wq, const float* __restrict__ Wk,
                           const float* __restrict__ Wv, const float* __restrict__ Ws,
                           const float* __restrict__ bq, const float* __restrict__ bk,
                           const float* __restrict__ bv, const float* __restrict__ bs,
                           ushort_t* __restrict__ Wt, float* __restrict__ bcat, int K) {
    int idx = blockIdx.x * 256 + threadIdx.x;
    int total = K * QKV_COLS;
    if (idx < total) {
        int c = idx / K, k = idx % K;
        float v;
        if (c < 256)      v = Wq[k * 256 + c];
        else if (c < 512) v = Wk[k * 256 + (c - 256)];
        else if (c < 768) v = Wv[k * 256 + (c - 512)];
        else              v = Ws[k * 64  + (c - 768)];
        Wt[idx] = bf16rne(v);
    }
    if (idx < QKV_COLS) {
        float b;
        if (idx < 256)      b = bq[idx];
        else if (idx < 512) b = bk[idx - 256];
        else if (idx < 768) b = bv[idx - 512];
        else                b = bs[idx - 768];
        bcat[idx] = b;
    }
}

// ---------------------------------------------------------------------------
// bf16 MFMA GEMM: C[N x 832] = A[N x K] @ W[K x 832] + bias
// A: bf16 [N x K] row-major. Wt: bf16 [832 x K] (transposed). Tile 128x64.
// cols [0,768) -> qkvb (bf16, row stride 768); cols [768,832) -> skipf (fp32).
// 256 threads = 4 waves; wave w owns rows w*32..w*32+32 of the tile.
// ---------------------------------------------------------------------------
template <int K>
__global__ __launch_bounds__(256) void gemm_mfma(const ushort_t* __restrict__ A,
                                                 const ushort_t* __restrict__ Wt,
                                                 const float* __restrict__ bias,
                                                 ushort_t* __restrict__ qkvb,
                                                 float* __restrict__ skipf, int N) {
    constexpr int KP = K + 8;      // padded LDS row stride (bf16 units); KP*2 % 16 == 0
    constexpr int KC = K / 8;      // 16B chunks per row
    __shared__ ushort_t As[128 * KP] __attribute__((aligned(16)));
    __shared__ ushort_t Bs[64 * KP] __attribute__((aligned(16)));

    const int t = threadIdx.x;
    const int base_r = blockIdx.x * 128;
    const int base_c = blockIdx.y * 64;

    // stage A tile (128 x K), 16B vector loads
#pragma unroll
    for (int i = 0; i < (128 * KC) / 256; ++i) {
        int idx = t + i * 256;
        int row = idx / KC, c = idx % KC;
        int gr = base_r + row;
        uint4 val = make_uint4(0u, 0u, 0u, 0u);
        if (gr < N) val = *(const uint4*)(A + (size_t)gr * K + c * 8);
        *(uint4*)(As + row * KP + c * 8) = val;
    }
    // stage B tile (64 cols of Wt, each K bf16)
#pragma unroll
    for (int i = 0; i < (64 * KC) / 256; ++i) {
        int idx = t + i * 256;
        int n = idx / KC, c = idx % KC;
        *(uint4*)(Bs + n * KP + c * 8) =
            *(const uint4*)(Wt + (size_t)(base_c + n) * K + c * 8);
    }
    __syncthreads();

    const int wave = t >> 6, lane = t & 63;
    const int quad = lane >> 4, m16 = lane & 15;

    floatx4 acc[2][4];
#pragma unroll
    for (int rt = 0; rt < 2; ++rt)
#pragma unroll
        for (int ct = 0; ct < 4; ++ct) acc[rt][ct] = (floatx4){0.f, 0.f, 0.f, 0.f};

#pragma unroll
    for (int kc = 0; kc < K / 32; ++kc) {
        int ko = kc * 32 + quad * 8;
        short8 a0 = *(const short8*)(As + (wave * 32 + m16) * KP + ko);
        short8 a1 = *(const short8*)(As + (wave * 32 + 16 + m16) * KP + ko);
#pragma unroll
        for (int ct = 0; ct < 4; ++ct) {
            short8 b = *(const short8*)(Bs + (ct * 16 + m16) * KP + ko);
            acc[0][ct] = __builtin_amdgcn_mfma_f32_16x16x32_bf16(a0, b, acc[0][ct], 0, 0, 0);
            acc[1][ct] = __builtin_amdgcn_mfma_f32_16x16x32_bf16(a1, b, acc[1][ct], 0, 0, 0);
        }
    }

    // epilogue: C[row][col], col = base_c + ct*16 + m16, row = base_r + wave*32 + rt*16 + quad*4 + r
    const bool is_skip = (base_c >= QKV_B);
#pragma unroll
    for (int ct = 0; ct < 4; ++ct) {
        int gcol = base_c + ct * 16 + m16;
        float bb = bias[gcol];
#pragma unroll
        for (int rt = 0; rt < 2; ++rt) {
#pragma unroll
            for (int r = 0; r < 4; ++r) {
                int grow = base_r + wave * 32 + rt * 16 + quad * 4 + r;
                if (grow < N) {
                    float vres = acc[rt][ct][r] + bb;
                    if (is_skip)
                        skipf[(size_t)grow * HIDDEN + (gcol - QKV_B)] = vres;
                    else
                        qkvb[(size_t)grow * QKV_B + gcol] = bf16rne(vres);
                }
            }
        }
    }
}

// ---------------------------------------------------------------------------
// TransformerConv aggregation: one wave per dst node; q/k/v bf16, skip fp32.
// lane holds dims [4*lane, 4*lane+4) of the 256-dim q/k/v; head = lane>>4.
// out = relu( mean_h( sum_e softmax(qk/8) * v ) + skip )   (bias folded in skip)
// ---------------------------------------------------------------------------
template <bool OUT_BF16>
__global__ __launch_bounds__(256) void attn_agg(const ushort_t* __restrict__ qkvb,
                                                const float* __restrict__ skipf,
                                                const int* __restrict__ rowptr,
                                                const int* __restrict__ col,
                                                void* __restrict__ hout) {
    int node = blockIdx.x * 4 + threadIdx.y;
    if (node >= N_NODES) return;
    int lane = threadIdx.x;
    const ushort_t* row = qkvb + (size_t)node * QKV_B;
    float4 q = bf4_unpack(*(const uint2*)(row + lane * 4));
    float ax = 0.f, ay = 0.f, az = 0.f, aw = 0.f, z = 0.f;
    int beg = rowptr[node], end = rowptr[node + 1];
    for (int e = beg; e < end; ++e) {
        int s = col[e];
        const ushort_t* srow = qkvb + (size_t)s * QKV_B;
        float4 kv = bf4_unpack(*(const uint2*)(srow + 256 + lane * 4));
        float4 vv = bf4_unpack(*(const uint2*)(srow + 512 + lane * 4));
        float d = q.x * kv.x + q.y * kv.y + q.z * kv.z + q.w * kv.w;
        d += __shfl_xor(d, 1);
        d += __shfl_xor(d, 2);
        d += __shfl_xor(d, 4);
        d += __shfl_xor(d, 8);
        float p = __expf(d * 0.125f);   // s/sqrt(64); |s|<1 so no max-shift needed
        z += p;
        ax = fmaf(p, vv.x, ax); ay = fmaf(p, vv.y, ay);
        az = fmaf(p, vv.z, az); aw = fmaf(p, vv.w, aw);
    }
    float inv = (z > 0.f) ? (1.f / z) : 0.f;
    ax *= inv; ay *= inv; az *= inv; aw *= inv;
    // mean over heads: lanes l, l+16, l+32, l+48 hold the same local dim
    ax += __shfl_xor(ax, 16); ax += __shfl_xor(ax, 32);
    ay += __shfl_xor(ay, 16); ay += __shfl_xor(ay, 32);
    az += __shfl_xor(az, 16); az += __shfl_xor(az, 32);
    aw += __shfl_xor(aw, 16); aw += __shfl_xor(aw, 32);
    if (lane < 16) {
        float4 sk = *(const float4*)(skipf + (size_t)node * HIDDEN + lane * 4);
        float ox = fmaxf(ax * 0.25f + sk.x, 0.f);
        float oy = fmaxf(ay * 0.25f + sk.y, 0.f);
        float oz = fmaxf(az * 0.25f + sk.z, 0.f);
        float ow = fmaxf(aw * 0.25f + sk.w, 0.f);
        if (OUT_BF16) {
            uint2 u;
            u.x = (uint_t)bf16rne(ox) | ((uint_t)bf16rne(oy) << 16);
            u.y = (uint_t)bf16rne(oz) | ((uint_t)bf16rne(ow) << 16);
            *(uint2*)((ushort_t*)hout + (size_t)node * HIDDEN + lane * 4) = u;
        } else {
            float4 o = make_float4(ox, oy, oz, ow);
            *(float4*)((float*)hout + (size_t)node * HIDDEN + lane * 4) = o;
        }
    }
}

// ---------------------------------------------------------------------------
// Per-graph mean pool (batch is sorted -> binary search boundaries, no atomics)
// ---------------------------------------------------------------------------
__global__ void pool_mean(const float* __restrict__ h, const int* __restrict__ batch,
                          float* __restrict__ gsum, int* __restrict__ gcnt) {
    int g = blockIdx.x;
    int lo = 0, hi = N_NODES;
    while (lo < hi) { int mid = (lo + hi) >> 1; if (batch[mid] < g) lo = mid + 1; else hi = mid; }
    int start = lo;
    hi = N_NODES;
    while (lo < hi) { int mid = (lo + hi) >> 1; if (batch[mid] < g + 1) lo = mid + 1; else hi = mid; }
    int end = lo;
    int t = threadIdx.x;
    int d = t & 63, chunk = t >> 6;   // 256 threads: 4 chunks x 64 dims
    float acc = 0.f;
    for (int n = start + chunk; n < end; n += 4) acc += h[(size_t)n * HIDDEN + d];
    __shared__ float sh[256];
    sh[t] = acc;
    __syncthreads();
    if (chunk == 0) {
        gsum[g * HIDDEN + d] = sh[d] + sh[64 + d] + sh[128 + d] + sh[192 + d];
        if (d == 0) gcnt[g] = end - start;
    }
}

// ---------------------------------------------------------------------------
// Final MLP head: one block (64 threads) per graph
// ---------------------------------------------------------------------------
__global__ __launch_bounds__(64) void mlp_head(const float* __restrict__ gsum,
                                               const int* __restrict__ gcnt,
                                               const float* __restrict__ gf,
                                               const float* __restrict__ gW1, const float* __restrict__ gb1,
                                               const float* __restrict__ gW2, const float* __restrict__ gb2,
                                               const float* __restrict__ hW1, const float* __restrict__ hb1,
                                               const float* __restrict__ hW2, const float* __restrict__ hb2,
                                               float* __restrict__ out) {
    int g = blockIdx.x;
    int t = threadIdx.x;   // 64 threads
    __shared__ float gfs[GLOBAL_DIM];
    __shared__ float g1[HIDDEN];
    __shared__ float fused[2 * HIDDEN];
    __shared__ float h1s[HIDDEN];
    for (int i = t; i < GLOBAL_DIM; i += 64) gfs[i] = gf[(size_t)g * GLOBAL_DIM + i];
    float cnt = (float)gcnt[g];
    cnt = fmaxf(cnt, 1.0f);
    fused[t] = gsum[g * HIDDEN + t] / cnt;   // patch_emb
    __syncthreads();
    float acc = gb1[t];
    for (int k = 0; k < GLOBAL_DIM; ++k) acc = fmaf(gfs[k], gW1[k * HIDDEN + t], acc);
    g1[t] = fmaxf(acc, 0.f);
    __syncthreads();
    acc = gb2[t];
    for (int k = 0; k < HIDDEN; ++k) acc = fmaf(g1[k], gW2[k * HIDDEN + t], acc);
    fused[HIDDEN + t] = fmaxf(acc, 0.f);
    __syncthreads();
    acc = hb1[t];
    for (int k = 0; k < 2 * HIDDEN; ++k) acc = fmaf(fused[k], hW1[k * HIDDEN + t], acc);
    h1s[t] = fmaxf(acc, 0.f);
    __syncthreads();
    if (t < N_CLASSES) {
        float o = hb2[t];
        for (int k = 0; k < HIDDEN; ++k) o = fmaf(h1s[k], hW2[k * N_CLASSES + t], o);
        out[(size_t)g * N_CLASSES + t] = o;
    }
}

// ---------------------------------------------------------------------------
extern "C" void kernel_launch(void* const* d_in, const int* in_sizes, int n_in,
                              void* d_out, int out_size, void* d_ws, size_t ws_size,
                              hipStream_t stream) {
    const float* x        = (const float*)d_in[0];
    const int*   eidx     = (const int*)d_in[1];
    const int*   batch    = (const int*)d_in[2];
    const float* gfeats   = (const float*)d_in[3];
    const float* c1_Wq = (const float*)d_in[4];  const float* c1_bq = (const float*)d_in[5];
    const float* c1_Wk = (const float*)d_in[6];  const float* c1_bk = (const float*)d_in[7];
    const float* c1_Wv = (const float*)d_in[8];  const float* c1_bv = (const float*)d_in[9];
    const float* c1_Ws = (const float*)d_in[10]; const float* c1_bs = (const float*)d_in[11];
    const float* c2_Wq = (const float*)d_in[12]; const float* c2_bq = (const float*)d_in[13];
    const float* c2_Wk = (const float*)d_in[14]; const float* c2_bk = (const float*)d_in[15];
    const float* c2_Wv = (const float*)d_in[16]; const float* c2_bv = (const float*)d_in[17];
    const float* c2_Ws = (const float*)d_in[18]; const float* c2_bs = (const float*)d_in[19];
    const float* g_W1 = (const float*)d_in[20]; const float* g_b1 = (const float*)d_in[21];
    const float* g_W2 = (const float*)d_in[22]; const float* g_b2 = (const float*)d_in[23];
    const float* h_W1 = (const float*)d_in[24]; const float* h_b1 = (const float*)d_in[25];
    const float* h_W2 = (const float*)d_in[26]; const float* h_b2 = (const float*)d_in[27];
    float* out = (float*)d_out;

    const int* srcp = eidx;
    const int* dstp = eidx + N_EDGES;

    // ---- workspace layout (all region sizes multiples of 16 B) ----
    char* base = (char*)d_ws;
    ushort_t* qkvb = (ushort_t*)base; base += (size_t)N_NODES * QKV_B * 2;   // 76.8 MB
    float*    skipf = (float*)base;   base += (size_t)N_NODES * HIDDEN * 4;  // 12.8 MB
    ushort_t* xb   = (ushort_t*)base; base += (size_t)N_NODES * IN_CH * 2;   // 12.8 MB
    ushort_t* h1b  = (ushort_t*)base; base += (size_t)N_NODES * HIDDEN * 2;  //  6.4 MB
    float*    h2   = (float*)base;    base += (size_t)N_NODES * HIDDEN * 4;  // 12.8 MB
    ushort_t* Wt   = (ushort_t*)base; base += (size_t)IN_CH * QKV_COLS * 2;  // 213 KB (max K)
    float*    bcat = (float*)base;    base += QKV_COLS * 4;
    float*    gsum = (float*)base;    base += N_GRAPHS * HIDDEN * 4;
    int* ib = (int*)base;
    size_t oi = 0;
    int* deg    = ib + oi; oi += N_NODES;
    int* incl   = ib + oi; oi += N_NODES;
    int* bsums  = ib + oi; oi += 64;
    int* boff   = ib + oi; oi += 64;
    int* rowptr = ib + oi; oi += N_NODES + 4;
    int* cur    = ib + oi; oi += N_NODES;
    int* colb   = ib + oi; oi += N_EDGES;
    int* gcnt   = ib + oi; oi += 64;

    const int NB1 = (N_NODES + 1023) / 1024;   // 49
    const int EB  = (N_EDGES + 255) / 256;     // 3125
    const int NBS = (N_NODES + 255) / 256;     // 196

    // ---- CSR build (shared by both conv layers) ----
    hipMemsetAsync(deg, 0, N_NODES * sizeof(int), stream);
    count_deg<<<EB, 256, 0, stream>>>(dstp, deg);
    scan1<<<NB1, 1024, 0, stream>>>(deg, incl, bsums, N_NODES);
    scan2<<<1, 64, 0, stream>>>(bsums, boff, NB1);
    scan3<<<NBS, 256, 0, stream>>>(deg, incl, boff, rowptr, cur, N_NODES);
    fill_col<<<EB, 256, 0, stream>>>(srcp, dstp, cur, colb);

    // ---- cast node features to bf16 ----
    cast_bf16_x8<<<(N_NODES * IN_CH / 8 + 255) / 256, 256, 0, stream>>>(x, xb, N_NODES * IN_CH / 8);

    dim3 gemm_grid((N_NODES + 127) / 128, QKV_COLS / 64);   // 391 x 13
    dim3 attn_block(64, 4);
    int attn_grid = (N_NODES + 3) / 4;                      // 12500

    // ---- conv1 ----
    concat_w_t<<<(IN_CH * QKV_COLS + 255) / 256, 256, 0, stream>>>(
        c1_Wq, c1_Wk, c1_Wv, c1_Ws, c1_bq, c1_bk, c1_bv, c1_bs, Wt, bcat, IN_CH);
    gemm_mfma<IN_CH><<<gemm_grid, 256, 0, stream>>>(xb, Wt, bcat, qkvb, skipf, N_NODES);
    attn_agg<true><<<attn_grid, attn_block, 0, stream>>>(qkvb, skipf, rowptr, colb, h1b);

    // ---- conv2 (reuses qkvb/skipf buffers) ----
    concat_w_t<<<(HIDDEN * QKV_COLS + 255) / 256, 256, 0, stream>>>(
        c2_Wq, c2_Wk, c2_Wv, c2_Ws, c2_bq, c2_bk, c2_bv, c2_bs, Wt, bcat, HIDDEN);
    gemm_mfma<HIDDEN><<<gemm_grid, 256, 0, stream>>>(h1b, Wt, bcat, qkvb, skipf, N_NODES);
    attn_agg<false><<<attn_grid, attn_block, 0, stream>>>(qkvb, skipf, rowptr, colb, h2);

    // ---- pool + head ----
    pool_mean<<<N_GRAPHS, 256, 0, stream>>>(h2, batch, gsum, gcnt);
    mlp_head<<<N_GRAPHS, 64, 0, stream>>>(gsum, gcnt, gfeats,
                                          g_W1, g_b1, g_W2, g_b2,
                                          h_W1, h_b1, h_W2, h_b2, out);
}

// Round 3
// 598.977 us; speedup vs baseline: 1.6998x; 1.1300x over previous
//
#include <hip/hip_runtime.h>
#include <hip/hip_bf16.h>
#include <math.h>

#define N_NODES   50000
#define N_EDGES   800000
#define N_GRAPHS  64
#define IN_CH     128
#define GLOBAL_DIM 256
#define HIDDEN    64
#define HEADS     4
#define N_CLASSES 10
#define QKV_COLS  832   // 256 q | 256 k | 256 v | 64 skip
#define QKV_B     768   // bf16 part (q|k|v)

typedef unsigned short ushort_t;
typedef unsigned int uint_t;
typedef __attribute__((ext_vector_type(8))) short short8;
typedef __attribute__((ext_vector_type(4))) float floatx4;

// ---------------------------------------------------------------------------
// helpers: bf16 <-> fp32 bit tricks (RNE for the cast down)
// ---------------------------------------------------------------------------
__device__ __forceinline__ ushort_t bf16rne(float f) {
    uint_t b = __float_as_uint(f);
    b += 0x7fffu + ((b >> 16) & 1u);
    return (ushort_t)(b >> 16);
}
__device__ __forceinline__ float4 bf4_unpack(uint_t lo, uint_t hi) {
    float4 f;
    f.x = __uint_as_float(lo << 16);
    f.y = __uint_as_float(lo & 0xffff0000u);
    f.z = __uint_as_float(hi << 16);
    f.w = __uint_as_float(hi & 0xffff0000u);
    return f;
}

// ---------------------------------------------------------------------------
// CSR build: deg -> inclusive scan -> rowptr/cursor -> fill col (src ids)
// ---------------------------------------------------------------------------
__global__ void count_deg(const int* __restrict__ dst, int* __restrict__ deg) {
    int e = blockIdx.x * 256 + threadIdx.x;
    if (e < N_EDGES) atomicAdd(&deg[dst[e]], 1);
}

__global__ void scan1(const int* __restrict__ deg, int* __restrict__ incl,
                      int* __restrict__ bsums, int n) {
    __shared__ int sh[1024];
    int t = threadIdx.x;
    int gid = blockIdx.x * 1024 + t;
    int v = (gid < n) ? deg[gid] : 0;
    sh[t] = v;
    __syncthreads();
    for (int off = 1; off < 1024; off <<= 1) {
        int tmp = (t >= off) ? sh[t - off] : 0;
        __syncthreads();
        sh[t] += tmp;
        __syncthreads();
    }
    if (gid < n) incl[gid] = sh[t];
    if (t == 1023) bsums[blockIdx.x] = sh[1023];
}

__global__ void scan2(const int* __restrict__ bsums, int* __restrict__ boff, int nb) {
    if (blockIdx.x == 0 && threadIdx.x == 0) {
        int acc = 0;
        for (int i = 0; i < nb; ++i) { boff[i] = acc; acc += bsums[i]; }
    }
}

__global__ void scan3(const int* __restrict__ deg, const int* __restrict__ incl,
                      const int* __restrict__ boff, int* __restrict__ rowptr,
                      int* __restrict__ cur, int n) {
    int gid = blockIdx.x * 256 + threadIdx.x;
    if (gid < n) {
        int b = gid >> 10;
        int in = incl[gid] + boff[b];
        int ex = in - deg[gid];
        rowptr[gid] = ex;
        cur[gid] = ex;
        if (gid == n - 1) rowptr[n] = in;
    }
}

__global__ void fill_col(const int* __restrict__ src, const int* __restrict__ dst,
                         int* __restrict__ cur, int* __restrict__ col) {
    int e = blockIdx.x * 256 + threadIdx.x;
    if (e < N_EDGES) {
        int d = dst[e];
        int pos = atomicAdd(&cur[d], 1);
        col[pos] = src[e];
    }
}

// ---------------------------------------------------------------------------
// Concatenate + transpose weights: Wt[c][k] (bf16), c in [0,832), plus bcat fp32
// ---------------------------------------------------------------------------
__global__ void concat_w_t(const float* __restrict__ Wq, const float* __restrict__ Wk,
                           const float* __restrict__ Wv, const float* __restrict__ Ws,
                           const float* __restrict__ bq, const float* __restrict__ bk,
                           const float* __restrict__ bv, const float* __restrict__ bs,
                           ushort_t* __restrict__ Wt, float* __restrict__ bcat, int K) {
    int idx = blockIdx.x * 256 + threadIdx.x;
    int total = K * QKV_COLS;
    if (idx < total) {
        int c = idx / K, k = idx % K;
        float v;
        if (c < 256)      v = Wq[k * 256 + c];
        else if (c < 512) v = Wk[k * 256 + (c - 256)];
        else if (c < 768) v = Wv[k * 256 + (c - 512)];
        else              v = Ws[k * 64  + (c - 768)];
        Wt[idx] = bf16rne(v);
    }
    if (idx < QKV_COLS) {
        float b;
        if (idx < 256)      b = bq[idx];
        else if (idx < 512) b = bk[idx - 256];
        else if (idx < 768) b = bv[idx - 512];
        else                b = bs[idx - 768];
        bcat[idx] = b;
    }
}

// ---------------------------------------------------------------------------
// bf16 MFMA GEMM, column-tile loop INSIDE the block (A staged once).
// C[N x 832] = A[N x K] @ Wt^T + bias.  Row tile = 64, grid = ceil(N/64).
// A is fp32 (conv1, cast during staging) or bf16 (conv2).
// cols [0,768) -> qkvb bf16 (row stride 768); cols [768,832) -> skipf fp32.
// 256 threads = 4 waves; wave w owns rows w*16..w*16+16 of the tile.
// ---------------------------------------------------------------------------
template <int K, bool A_FP32>
__global__ __launch_bounds__(256) void gemm_mfma2(const void* __restrict__ Av,
                                                  const ushort_t* __restrict__ Wt,
                                                  const float* __restrict__ bias,
                                                  ushort_t* __restrict__ qkvb,
                                                  float* __restrict__ skipf, int N) {
    constexpr int KP = K + 8;      // padded LDS row stride (bf16 units)
    constexpr int C8 = K / 8;      // 16B bf16 chunks per row
    __shared__ ushort_t As[64 * KP] __attribute__((aligned(16)));
    __shared__ ushort_t Bs[64 * KP] __attribute__((aligned(16)));

    const int t = threadIdx.x;
    const int base_r = blockIdx.x * 64;

    // ---- stage A tile (64 x K) once ----
    if (A_FP32) {
        const float* A = (const float*)Av;
        constexpr int C4 = K / 4;  // float4 chunks per row
#pragma unroll
        for (int i = 0; i < (64 * C4) / 256; ++i) {
            int idx = t + i * 256;
            int r = idx / C4, c = idx % C4;
            int gr = base_r + r;
            float4 av = make_float4(0.f, 0.f, 0.f, 0.f);
            if (gr < N) av = *(const float4*)(A + (size_t)gr * K + c * 4);
            uint2 u;
            u.x = (uint_t)bf16rne(av.x) | ((uint_t)bf16rne(av.y) << 16);
            u.y = (uint_t)bf16rne(av.z) | ((uint_t)bf16rne(av.w) << 16);
            *(uint2*)(As + r * KP + c * 4) = u;
        }
    } else {
        const ushort_t* A = (const ushort_t*)Av;
#pragma unroll
        for (int i = 0; i < (64 * C8) / 256; ++i) {
            int idx = t + i * 256;
            int r = idx / C8, c = idx % C8;
            int gr = base_r + r;
            uint4 val = make_uint4(0u, 0u, 0u, 0u);
            if (gr < N) val = *(const uint4*)(A + (size_t)gr * K + c * 8);
            *(uint4*)(As + r * KP + c * 8) = val;
        }
    }

    const int wave = t >> 6, lane = t & 63;
    const int quad = lane >> 4, m16 = lane & 15;

    // ---- loop over 13 column tiles; Wt (<=213 KB) is L2-resident ----
    for (int ct = 0; ct < QKV_COLS / 64; ++ct) {
        const int base_c = ct * 64;
        __syncthreads();   // prev iter's MFMA done reading Bs (iter0: A staged)
#pragma unroll
        for (int i = 0; i < (64 * C8) / 256; ++i) {
            int idx = t + i * 256;
            int n = idx / C8, c = idx % C8;
            *(uint4*)(Bs + n * KP + c * 8) =
                *(const uint4*)(Wt + (size_t)(base_c + n) * K + c * 8);
        }
        __syncthreads();

        floatx4 acc[4];
#pragma unroll
        for (int c2 = 0; c2 < 4; ++c2) acc[c2] = (floatx4){0.f, 0.f, 0.f, 0.f};
#pragma unroll
        for (int kc = 0; kc < K / 32; ++kc) {
            int ko = kc * 32 + quad * 8;
            short8 a = *(const short8*)(As + (wave * 16 + m16) * KP + ko);
#pragma unroll
            for (int c2 = 0; c2 < 4; ++c2) {
                short8 b = *(const short8*)(Bs + (c2 * 16 + m16) * KP + ko);
                acc[c2] = __builtin_amdgcn_mfma_f32_16x16x32_bf16(a, b, acc[c2], 0, 0, 0);
            }
        }

        // epilogue: col = base_c + c2*16 + m16, row = base_r + wave*16 + quad*4 + r
        if (base_c < QKV_B) {
#pragma unroll
            for (int c2 = 0; c2 < 4; ++c2) {
                int gcol = base_c + c2 * 16 + m16;
                float bb = bias[gcol];
#pragma unroll
                for (int r = 0; r < 4; ++r) {
                    int grow = base_r + wave * 16 + quad * 4 + r;
                    if (grow < N)
                        qkvb[(size_t)grow * QKV_B + gcol] = bf16rne(acc[c2][r] + bb);
                }
            }
        } else {
#pragma unroll
            for (int c2 = 0; c2 < 4; ++c2) {
                int lcol = c2 * 16 + m16;
                float bb = bias[QKV_B + lcol];
#pragma unroll
                for (int r = 0; r < 4; ++r) {
                    int grow = base_r + wave * 16 + quad * 4 + r;
                    if (grow < N)
                        skipf[(size_t)grow * HIDDEN + lcol] = acc[c2][r] + bb;
                }
            }
        }
    }
}

// ---------------------------------------------------------------------------
// TransformerConv aggregation v2: one wave per dst node, HALF-WAVE per edge.
// half = lane>>5 handles edges beg+half, beg+half+2, ...
// sl = lane&31 owns dims [8*sl, 8*sl+8): one 16B k-load + one 16B v-load/edge.
// head h = sl>>3 (8 lanes per head); dot-reduce = shfl_xor 1,2,4.
// out = relu( mean_h( sum_e softmax(qk/8) * v ) + skip )
// ---------------------------------------------------------------------------
template <bool OUT_BF16>
__global__ __launch_bounds__(256) void attn_agg2(const ushort_t* __restrict__ qkvb,
                                                 const float* __restrict__ skipf,
                                                 const int* __restrict__ rowptr,
                                                 const int* __restrict__ col,
                                                 void* __restrict__ hout) {
    int node = blockIdx.x * 4 + threadIdx.y;
    if (node >= N_NODES) return;
    int lane = threadIdx.x;
    int half = lane >> 5, sl = lane & 31;
    const ushort_t* row = qkvb + (size_t)node * QKV_B;
    uint4 qu = *(const uint4*)(row + sl * 8);
    float4 qa = bf4_unpack(qu.x, qu.y);
    float4 qb = bf4_unpack(qu.z, qu.w);
    float a0 = 0.f, a1 = 0.f, a2 = 0.f, a3 = 0.f;
    float a4 = 0.f, a5 = 0.f, a6 = 0.f, a7 = 0.f;
    float z = 0.f;
    int beg = rowptr[node], end = rowptr[node + 1];
    int e = beg + half;
    // 2 edges per half in flight (4 per wave)
    for (; e + 2 < end; e += 4) {
        int s0 = col[e], s1 = col[e + 2];
        const ushort_t* r0 = qkvb + (size_t)s0 * QKV_B + sl * 8;
        const ushort_t* r1 = qkvb + (size_t)s1 * QKV_B + sl * 8;
        uint4 k0 = *(const uint4*)(r0 + 256);
        uint4 v0 = *(const uint4*)(r0 + 512);
        uint4 k1 = *(const uint4*)(r1 + 256);
        uint4 v1 = *(const uint4*)(r1 + 512);
        float4 ka = bf4_unpack(k0.x, k0.y), kb = bf4_unpack(k0.z, k0.w);
        float d0 = qa.x * ka.x + qa.y * ka.y + qa.z * ka.z + qa.w * ka.w
                 + qb.x * kb.x + qb.y * kb.y + qb.z * kb.z + qb.w * kb.w;
        ka = bf4_unpack(k1.x, k1.y); kb = bf4_unpack(k1.z, k1.w);
        float d1 = qa.x * ka.x + qa.y * ka.y + qa.z * ka.z + qa.w * ka.w
                 + qb.x * kb.x + qb.y * kb.y + qb.z * kb.z + qb.w * kb.w;
        d0 += __shfl_xor(d0, 1); d1 += __shfl_xor(d1, 1);
        d0 += __shfl_xor(d0, 2); d1 += __shfl_xor(d1, 2);
        d0 += __shfl_xor(d0, 4); d1 += __shfl_xor(d1, 4);
        float p0 = __expf(d0 * 0.125f);
        float p1 = __expf(d1 * 0.125f);
        z += p0 + p1;
        float4 va = bf4_unpack(v0.x, v0.y), vb = bf4_unpack(v0.z, v0.w);
        a0 = fmaf(p0, va.x, a0); a1 = fmaf(p0, va.y, a1);
        a2 = fmaf(p0, va.z, a2); a3 = fmaf(p0, va.w, a3);
        a4 = fmaf(p0, vb.x, a4); a5 = fmaf(p0, vb.y, a5);
        a6 = fmaf(p0, vb.z, a6); a7 = fmaf(p0, vb.w, a7);
        va = bf4_unpack(v1.x, v1.y); vb = bf4_unpack(v1.z, v1.w);
        a0 = fmaf(p1, va.x, a0); a1 = fmaf(p1, va.y, a1);
        a2 = fmaf(p1, va.z, a2); a3 = fmaf(p1, va.w, a3);
        a4 = fmaf(p1, vb.x, a4); a5 = fmaf(p1, vb.y, a5);
        a6 = fmaf(p1, vb.z, a6); a7 = fmaf(p1, vb.w, a7);
    }
    for (; e < end; e += 2) {
        int s0 = col[e];
        const ushort_t* r0 = qkvb + (size_t)s0 * QKV_B + sl * 8;
        uint4 k0 = *(const uint4*)(r0 + 256);
        uint4 v0 = *(const uint4*)(r0 + 512);
        float4 ka = bf4_unpack(k0.x, k0.y), kb = bf4_unpack(k0.z, k0.w);
        float d0 = qa.x * ka.x + qa.y * ka.y + qa.z * ka.z + qa.w * ka.w
                 + qb.x * kb.x + qb.y * kb.y + qb.z * kb.z + qb.w * kb.w;
        d0 += __shfl_xor(d0, 1);
        d0 += __shfl_xor(d0, 2);
        d0 += __shfl_xor(d0, 4);
        float p0 = __expf(d0 * 0.125f);
        z += p0;
        float4 va = bf4_unpack(v0.x, v0.y), vb = bf4_unpack(v0.z, v0.w);
        a0 = fmaf(p0, va.x, a0); a1 = fmaf(p0, va.y, a1);
        a2 = fmaf(p0, va.z, a2); a3 = fmaf(p0, va.w, a3);
        a4 = fmaf(p0, vb.x, a4); a5 = fmaf(p0, vb.y, a5);
        a6 = fmaf(p0, vb.z, a6); a7 = fmaf(p0, vb.w, a7);
    }
    // combine the two halves (each summed its own edge subset)
    z += __shfl_xor(z, 32);
    a0 += __shfl_xor(a0, 32); a1 += __shfl_xor(a1, 32);
    a2 += __shfl_xor(a2, 32); a3 += __shfl_xor(a3, 32);
    a4 += __shfl_xor(a4, 32); a5 += __shfl_xor(a5, 32);
    a6 += __shfl_xor(a6, 32); a7 += __shfl_xor(a7, 32);
    float inv = (z > 0.f) ? (1.f / z) : 0.f;
    a0 *= inv; a1 *= inv; a2 *= inv; a3 *= inv;
    a4 *= inv; a5 *= inv; a6 *= inv; a7 *= inv;
    // head mean: lanes {sl, sl^8, sl^16, sl^24} hold same within-head dim
    a0 += __shfl_xor(a0, 8); a0 += __shfl_xor(a0, 16);
    a1 += __shfl_xor(a1, 8); a1 += __shfl_xor(a1, 16);
    a2 += __shfl_xor(a2, 8); a2 += __shfl_xor(a2, 16);
    a3 += __shfl_xor(a3, 8); a3 += __shfl_xor(a3, 16);
    a4 += __shfl_xor(a4, 8); a4 += __shfl_xor(a4, 16);
    a5 += __shfl_xor(a5, 8); a5 += __shfl_xor(a5, 16);
    a6 += __shfl_xor(a6, 8); a6 += __shfl_xor(a6, 16);
    a7 += __shfl_xor(a7, 8); a7 += __shfl_xor(a7, 16);
    if (lane < 8) {   // lane holds output dims [8*lane, 8*lane+8)
        const float* sp = skipf + (size_t)node * HIDDEN + lane * 8;
        float4 s0 = *(const float4*)(sp);
        float4 s1 = *(const float4*)(sp + 4);
        float o0 = fmaxf(a0 * 0.25f + s0.x, 0.f);
        float o1 = fmaxf(a1 * 0.25f + s0.y, 0.f);
        float o2 = fmaxf(a2 * 0.25f + s0.z, 0.f);
        float o3 = fmaxf(a3 * 0.25f + s0.w, 0.f);
        float o4 = fmaxf(a4 * 0.25f + s1.x, 0.f);
        float o5 = fmaxf(a5 * 0.25f + s1.y, 0.f);
        float o6 = fmaxf(a6 * 0.25f + s1.z, 0.f);
        float o7 = fmaxf(a7 * 0.25f + s1.w, 0.f);
        if (OUT_BF16) {
            uint4 u;
            u.x = (uint_t)bf16rne(o0) | ((uint_t)bf16rne(o1) << 16);
            u.y = (uint_t)bf16rne(o2) | ((uint_t)bf16rne(o3) << 16);
            u.z = (uint_t)bf16rne(o4) | ((uint_t)bf16rne(o5) << 16);
            u.w = (uint_t)bf16rne(o6) | ((uint_t)bf16rne(o7) << 16);
            *(uint4*)((ushort_t*)hout + (size_t)node * HIDDEN + lane * 8) = u;
        } else {
            float* op = (float*)hout + (size_t)node * HIDDEN + lane * 8;
            *(float4*)(op)     = make_float4(o0, o1, o2, o3);
            *(float4*)(op + 4) = make_float4(o4, o5, o6, o7);
        }
    }
}

// ---------------------------------------------------------------------------
// Per-graph mean pool (batch is sorted -> binary search boundaries, no atomics)
// ---------------------------------------------------------------------------
__global__ void pool_mean(const float* __restrict__ h, const int* __restrict__ batch,
                          float* __restrict__ gsum, int* __restrict__ gcnt) {
    int g = blockIdx.x;
    int lo = 0, hi = N_NODES;
    while (lo < hi) { int mid = (lo + hi) >> 1; if (batch[mid] < g) lo = mid + 1; else hi = mid; }
    int start = lo;
    hi = N_NODES;
    while (lo < hi) { int mid = (lo + hi) >> 1; if (batch[mid] < g + 1) lo = mid + 1; else hi = mid; }
    int end = lo;
    int t = threadIdx.x;
    int d = t & 63, chunk = t >> 6;   // 256 threads: 4 chunks x 64 dims
    float acc = 0.f;
    for (int n = start + chunk; n < end; n += 4) acc += h[(size_t)n * HIDDEN + d];
    __shared__ float sh[256];
    sh[t] = acc;
    __syncthreads();
    if (chunk == 0) {
        gsum[g * HIDDEN + d] = sh[d] + sh[64 + d] + sh[128 + d] + sh[192 + d];
        if (d == 0) gcnt[g] = end - start;
    }
}

// ---------------------------------------------------------------------------
// Final MLP head: one block (64 threads) per graph
// ---------------------------------------------------------------------------
__global__ __launch_bounds__(64) void mlp_head(const float* __restrict__ gsum,
                                               const int* __restrict__ gcnt,
                                               const float* __restrict__ gf,
                                               const float* __restrict__ gW1, const float* __restrict__ gb1,
                                               const float* __restrict__ gW2, const float* __restrict__ gb2,
                                               const float* __restrict__ hW1, const float* __restrict__ hb1,
                                               const float* __restrict__ hW2, const float* __restrict__ hb2,
                                               float* __restrict__ out) {
    int g = blockIdx.x;
    int t = threadIdx.x;   // 64 threads
    __shared__ float gfs[GLOBAL_DIM];
    __shared__ float g1[HIDDEN];
    __shared__ float fused[2 * HIDDEN];
    __shared__ float h1s[HIDDEN];
    for (int i = t; i < GLOBAL_DIM; i += 64) gfs[i] = gf[(size_t)g * GLOBAL_DIM + i];
    float cnt = (float)gcnt[g];
    cnt = fmaxf(cnt, 1.0f);
    fused[t] = gsum[g * HIDDEN + t] / cnt;   // patch_emb
    __syncthreads();
    float acc = gb1[t];
    for (int k = 0; k < GLOBAL_DIM; ++k) acc = fmaf(gfs[k], gW1[k * HIDDEN + t], acc);
    g1[t] = fmaxf(acc, 0.f);
    __syncthreads();
    acc = gb2[t];
    for (int k = 0; k < HIDDEN; ++k) acc = fmaf(g1[k], gW2[k * HIDDEN + t], acc);
    fused[HIDDEN + t] = fmaxf(acc, 0.f);
    __syncthreads();
    acc = hb1[t];
    for (int k = 0; k < 2 * HIDDEN; ++k) acc = fmaf(fused[k], hW1[k * HIDDEN + t], acc);
    h1s[t] = fmaxf(acc, 0.f);
    __syncthreads();
    if (t < N_CLASSES) {
        float o = hb2[t];
        for (int k = 0; k < HIDDEN; ++k) o = fmaf(h1s[k], hW2[k * N_CLASSES + t], o);
        out[(size_t)g * N_CLASSES + t] = o;
    }
}

// ---------------------------------------------------------------------------
extern "C" void kernel_launch(void* const* d_in, const int* in_sizes, int n_in,
                              void* d_out, int out_size, void* d_ws, size_t ws_size,
                              hipStream_t stream) {
    const float* x        = (const float*)d_in[0];
    const int*   eidx     = (const int*)d_in[1];
    const int*   batch    = (const int*)d_in[2];
    const float* gfeats   = (const float*)d_in[3];
    const float* c1_Wq = (const float*)d_in[4];  const float* c1_bq = (const float*)d_in[5];
    const float* c1_Wk = (const float*)d_in[6];  const float* c1_bk = (const float*)d_in[7];
    const float* c1_Wv = (const float*)d_in[8];  const float* c1_bv = (const float*)d_in[9];
    const float* c1_Ws = (const float*)d_in[10]; const float* c1_bs = (const float*)d_in[11];
    const float* c2_Wq = (const float*)d_in[12]; const float* c2_bq = (const float*)d_in[13];
    const float* c2_Wk = (const float*)d_in[14]; const float* c2_bk = (const float*)d_in[15];
    const float* c2_Wv = (const float*)d_in[16]; const float* c2_bv = (const float*)d_in[17];
    const float* c2_Ws = (const float*)d_in[18]; const float* c2_bs = (const float*)d_in[19];
    const float* g_W1 = (const float*)d_in[20]; const float* g_b1 = (const float*)d_in[21];
    const float* g_W2 = (const float*)d_in[22]; const float* g_b2 = (const float*)d_in[23];
    const float* h_W1 = (const float*)d_in[24]; const float* h_b1 = (const float*)d_in[25];
    const float* h_W2 = (const float*)d_in[26]; const float* h_b2 = (const float*)d_in[27];
    float* out = (float*)d_out;

    const int* srcp = eidx;
    const int* dstp = eidx + N_EDGES;

    // ---- workspace layout (all region sizes multiples of 16 B) ----
    char* base = (char*)d_ws;
    ushort_t* qkvb = (ushort_t*)base; base += (size_t)N_NODES * QKV_B * 2;   // 76.8 MB
    float*    skipf = (float*)base;   base += (size_t)N_NODES * HIDDEN * 4;  // 12.8 MB
    ushort_t* h1b  = (ushort_t*)base; base += (size_t)N_NODES * HIDDEN * 2;  //  6.4 MB
    float*    h2   = (float*)base;    base += (size_t)N_NODES * HIDDEN * 4;  // 12.8 MB
    ushort_t* Wt   = (ushort_t*)base; base += (size_t)IN_CH * QKV_COLS * 2;  // 213 KB (max K)
    float*    bcat = (float*)base;    base += QKV_COLS * 4;
    float*    gsum = (float*)base;    base += N_GRAPHS * HIDDEN * 4;
    int* ib = (int*)base;
    size_t oi = 0;
    int* deg    = ib + oi; oi += N_NODES;
    int* incl   = ib + oi; oi += N_NODES;
    int* bsums  = ib + oi; oi += 64;
    int* boff   = ib + oi; oi += 64;
    int* rowptr = ib + oi; oi += N_NODES + 4;
    int* cur    = ib + oi; oi += N_NODES;
    int* colb   = ib + oi; oi += N_EDGES;
    int* gcnt   = ib + oi; oi += 64;

    const int NB1 = (N_NODES + 1023) / 1024;   // 49
    const int EB  = (N_EDGES + 255) / 256;     // 3125
    const int NBS = (N_NODES + 255) / 256;     // 196

    // ---- CSR build (shared by both conv layers) ----
    hipMemsetAsync(deg, 0, N_NODES * sizeof(int), stream);
    count_deg<<<EB, 256, 0, stream>>>(dstp, deg);
    scan1<<<NB1, 1024, 0, stream>>>(deg, incl, bsums, N_NODES);
    scan2<<<1, 64, 0, stream>>>(bsums, boff, NB1);
    scan3<<<NBS, 256, 0, stream>>>(deg, incl, boff, rowptr, cur, N_NODES);
    fill_col<<<EB, 256, 0, stream>>>(srcp, dstp, cur, colb);

    int gemm_grid = (N_NODES + 63) / 64;       // 782
    dim3 attn_block(64, 4);
    int attn_grid = (N_NODES + 3) / 4;         // 12500

    // ---- conv1 (A = x fp32, cast during LDS staging) ----
    concat_w_t<<<(IN_CH * QKV_COLS + 255) / 256, 256, 0, stream>>>(
        c1_Wq, c1_Wk, c1_Wv, c1_Ws, c1_bq, c1_bk, c1_bv, c1_bs, Wt, bcat, IN_CH);
    gemm_mfma2<IN_CH, true><<<gemm_grid, 256, 0, stream>>>(x, Wt, bcat, qkvb, skipf, N_NODES);
    attn_agg2<true><<<attn_grid, attn_block, 0, stream>>>(qkvb, skipf, rowptr, colb, h1b);

    // ---- conv2 (A = h1b bf16; reuses qkvb/skipf buffers) ----
    concat_w_t<<<(HIDDEN * QKV_COLS + 255) / 256, 256, 0, stream>>>(
        c2_Wq, c2_Wk, c2_Wv, c2_Ws, c2_bq, c2_bk, c2_bv, c2_bs, Wt, bcat, HIDDEN);
    gemm_mfma2<HIDDEN, false><<<gemm_grid, 256, 0, stream>>>(h1b, Wt, bcat, qkvb, skipf, N_NODES);
    attn_agg2<false><<<attn_grid, attn_block, 0, stream>>>(qkvb, skipf, rowptr, colb, h2);

    // ---- pool + head ----
    pool_mean<<<N_GRAPHS, 256, 0, stream>>>(h2, batch, gsum, gcnt);
    mlp_head<<<N_GRAPHS, 64, 0, stream>>>(gsum, gcnt, gfeats,
                                          g_W1, g_b1, g_W2, g_b2,
                                          h_W1, h_b1, h_W2, h_b2, out);
}

// Round 4
// 567.413 us; speedup vs baseline: 1.7944x; 1.0556x over previous
//
#include <hip/hip_runtime.h>
#include <hip/hip_bf16.h>
#include <math.h>

#define N_NODES   50000
#define N_EDGES   800000
#define N_GRAPHS  64
#define IN_CH     128
#define GLOBAL_DIM 256
#define HIDDEN    64
#define HEADS     4
#define N_CLASSES 10
#define QKV_COLS  832   // 256 q | 256 k | 256 v | 64 skip

typedef unsigned short ushort_t;
typedef unsigned int uint_t;
typedef unsigned char uchar_t;
typedef __attribute__((ext_vector_type(8))) short short8;
typedef __attribute__((ext_vector_type(4))) float floatx4;
typedef __attribute__((ext_vector_type(2))) float floatx2;

// ---------------------------------------------------------------------------
// helpers
// ---------------------------------------------------------------------------
__device__ __forceinline__ ushort_t bf16rne(float f) {
    uint_t b = __float_as_uint(f);
    b += 0x7fffu + ((b >> 16) & 1u);
    return (ushort_t)(b >> 16);
}
__device__ __forceinline__ float4 bf4_unpack(uint_t lo, uint_t hi) {
    float4 f;
    f.x = __uint_as_float(lo << 16);
    f.y = __uint_as_float(lo & 0xffff0000u);
    f.z = __uint_as_float(hi << 16);
    f.w = __uint_as_float(hi & 0xffff0000u);
    return f;
}
__device__ __forceinline__ uchar_t fp8e4m3(float f) {
    int v = __builtin_amdgcn_cvt_pk_fp8_f32(f, 0.f, 0, false);
    return (uchar_t)(v & 0xff);
}

// ---------------------------------------------------------------------------
// CSR build: deg -> inclusive scan -> rowptr/cursor -> fill col (src ids)
// ---------------------------------------------------------------------------
__global__ void count_deg(const int* __restrict__ dst, int* __restrict__ deg) {
    int e = blockIdx.x * 256 + threadIdx.x;
    if (e < N_EDGES) atomicAdd(&deg[dst[e]], 1);
}

__global__ void scan1(const int* __restrict__ deg, int* __restrict__ incl,
                      int* __restrict__ bsums, int n) {
    __shared__ int sh[1024];
    int t = threadIdx.x;
    int gid = blockIdx.x * 1024 + t;
    int v = (gid < n) ? deg[gid] : 0;
    sh[t] = v;
    __syncthreads();
    for (int off = 1; off < 1024; off <<= 1) {
        int tmp = (t >= off) ? sh[t - off] : 0;
        __syncthreads();
        sh[t] += tmp;
        __syncthreads();
    }
    if (gid < n) incl[gid] = sh[t];
    if (t == 1023) bsums[blockIdx.x] = sh[1023];
}

__global__ void scan2(const int* __restrict__ bsums, int* __restrict__ boff, int nb) {
    int t = threadIdx.x;   // 64 threads, nb <= 64
    int v = (t < nb) ? bsums[t] : 0;
    int incl = v;
#pragma unroll
    for (int off = 1; off < 64; off <<= 1) {
        int u = __shfl_up(incl, off);
        if (t >= off) incl += u;
    }
    if (t < nb) boff[t] = incl - v;   // exclusive
}

__global__ void scan3(const int* __restrict__ deg, const int* __restrict__ incl,
                      const int* __restrict__ boff, int* __restrict__ rowptr,
                      int* __restrict__ cur, int n) {
    int gid = blockIdx.x * 256 + threadIdx.x;
    if (gid < n) {
        int b = gid >> 10;
        int in = incl[gid] + boff[b];
        int ex = in - deg[gid];
        rowptr[gid] = ex;
        cur[gid] = ex;
        if (gid == n - 1) rowptr[n] = in;
    }
}

__global__ void fill_col(const int* __restrict__ src, const int* __restrict__ dst,
                         int* __restrict__ cur, int* __restrict__ col) {
    int e = blockIdx.x * 256 + threadIdx.x;
    if (e < N_EDGES) {
        int d = dst[e];
        int pos = atomicAdd(&cur[d], 1);
        col[pos] = src[e];
    }
}

// ---------------------------------------------------------------------------
// Concatenate + transpose weights: Wt[c][k] (bf16), c in [0,832), plus bcat fp32
// ---------------------------------------------------------------------------
__global__ void concat_w_t(const float* __restrict__ Wq, const float* __restrict__ Wk,
                           const float* __restrict__ Wv, const float* __restrict__ Ws,
                           const float* __restrict__ bq, const float* __restrict__ bk,
                           const float* __restrict__ bv, const float* __restrict__ bs,
                           ushort_t* __restrict__ Wt, float* __restrict__ bcat, int K) {
    int idx = blockIdx.x * 256 + threadIdx.x;
    int total = K * QKV_COLS;
    if (idx < total) {
        int c = idx / K, k = idx % K;
        float v;
        if (c < 256)      v = Wq[k * 256 + c];
        else if (c < 512) v = Wk[k * 256 + (c - 256)];
        else if (c < 768) v = Wv[k * 256 + (c - 512)];
        else              v = Ws[k * 64  + (c - 768)];
        Wt[idx] = bf16rne(v);
    }
    if (idx < QKV_COLS) {
        float b;
        if (idx < 256)      b = bq[idx];
        else if (idx < 512) b = bk[idx - 256];
        else if (idx < 768) b = bv[idx - 512];
        else                b = bs[idx - 768];
        bcat[idx] = b;
    }
}

// ---------------------------------------------------------------------------
// bf16 MFMA GEMM, 128-row tile, column-tile loop inside (A staged once).
// Outputs split: cols [0,256) -> qb bf16 [N,256]
//                cols [256,768) -> kvb fp8, per-node 512B row:
//                    chunk layout: byte 16*(c>>3)+(c&7)     = k dim c
//                                  byte 16*(c>>3)+8+(c&7)   = v dim c
//                cols [768,832) -> skipf fp32 [N,64]
// 256 threads = 4 waves; wave w owns rows w*32..w*32+32 of the tile.
// ---------------------------------------------------------------------------
template <int K, bool A_FP32>
__global__ __launch_bounds__(256) void gemm_mfma3(const void* __restrict__ Av,
                                                  const ushort_t* __restrict__ Wt,
                                                  const float* __restrict__ bias,
                                                  ushort_t* __restrict__ qb,
                                                  uchar_t* __restrict__ kvb,
                                                  float* __restrict__ skipf, int N) {
    constexpr int KP = K + 8;      // padded LDS row stride (bf16 units)
    constexpr int C8 = K / 8;      // 16B bf16 chunks per row
    __shared__ ushort_t As[128 * KP] __attribute__((aligned(16)));
    __shared__ ushort_t Bs[64 * KP] __attribute__((aligned(16)));

    const int t = threadIdx.x;
    const int base_r = blockIdx.x * 128;

    // ---- stage A tile (128 x K) once ----
    if (A_FP32) {
        const float* A = (const float*)Av;
        constexpr int C4 = K / 4;
#pragma unroll
        for (int i = 0; i < (128 * C4) / 256; ++i) {
            int idx = t + i * 256;
            int r = idx / C4, c = idx % C4;
            int gr = base_r + r;
            float4 av = make_float4(0.f, 0.f, 0.f, 0.f);
            if (gr < N) av = *(const float4*)(A + (size_t)gr * K + c * 4);
            uint2 u;
            u.x = (uint_t)bf16rne(av.x) | ((uint_t)bf16rne(av.y) << 16);
            u.y = (uint_t)bf16rne(av.z) | ((uint_t)bf16rne(av.w) << 16);
            *(uint2*)(As + r * KP + c * 4) = u;
        }
    } else {
        const ushort_t* A = (const ushort_t*)Av;
#pragma unroll
        for (int i = 0; i < (128 * C8) / 256; ++i) {
            int idx = t + i * 256;
            int r = idx / C8, c = idx % C8;
            int gr = base_r + r;
            uint4 val = make_uint4(0u, 0u, 0u, 0u);
            if (gr < N) val = *(const uint4*)(A + (size_t)gr * K + c * 8);
            *(uint4*)(As + r * KP + c * 8) = val;
        }
    }

    const int wave = t >> 6, lane = t & 63;
    const int quad = lane >> 4, m16 = lane & 15;

    // ---- loop over 13 column tiles; Wt (<=213 KB) is L2-resident ----
    for (int ct = 0; ct < QKV_COLS / 64; ++ct) {
        const int base_c = ct * 64;
        __syncthreads();   // prev iter's MFMA done reading Bs (iter0: A staged)
#pragma unroll
        for (int i = 0; i < (64 * C8) / 256; ++i) {
            int idx = t + i * 256;
            int n = idx / C8, c = idx % C8;
            *(uint4*)(Bs + n * KP + c * 8) =
                *(const uint4*)(Wt + (size_t)(base_c + n) * K + c * 8);
        }
        __syncthreads();

        floatx4 acc[2][4];
#pragma unroll
        for (int rt = 0; rt < 2; ++rt)
#pragma unroll
            for (int c2 = 0; c2 < 4; ++c2) acc[rt][c2] = (floatx4){0.f, 0.f, 0.f, 0.f};
#pragma unroll
        for (int kc = 0; kc < K / 32; ++kc) {
            int ko = kc * 32 + quad * 8;
            short8 a0 = *(const short8*)(As + (wave * 32 + m16) * KP + ko);
            short8 a1 = *(const short8*)(As + (wave * 32 + 16 + m16) * KP + ko);
#pragma unroll
            for (int c2 = 0; c2 < 4; ++c2) {
                short8 b = *(const short8*)(Bs + (c2 * 16 + m16) * KP + ko);
                acc[0][c2] = __builtin_amdgcn_mfma_f32_16x16x32_bf16(a0, b, acc[0][c2], 0, 0, 0);
                acc[1][c2] = __builtin_amdgcn_mfma_f32_16x16x32_bf16(a1, b, acc[1][c2], 0, 0, 0);
            }
        }

        // epilogue: col = base_c + c2*16 + m16, row = base_r + wave*32 + rt*16 + quad*4 + r
#pragma unroll
        for (int c2 = 0; c2 < 4; ++c2) {
            int gcol = base_c + c2 * 16 + m16;
            float bb = bias[gcol];
#pragma unroll
            for (int rt = 0; rt < 2; ++rt) {
#pragma unroll
                for (int r = 0; r < 4; ++r) {
                    int grow = base_r + wave * 32 + rt * 16 + quad * 4 + r;
                    if (grow >= N) continue;
                    float vres = acc[rt][c2][r] + bb;
                    if (ct < 4) {
                        qb[(size_t)grow * 256 + gcol] = bf16rne(vres);
                    } else if (ct < 8) {
                        int c = gcol - 256;
                        kvb[(size_t)grow * 512 + 16 * (c >> 3) + (c & 7)] = fp8e4m3(vres);
                    } else if (ct < 12) {
                        int c = gcol - 512;
                        kvb[(size_t)grow * 512 + 16 * (c >> 3) + 8 + (c & 7)] = fp8e4m3(vres);
                    } else {
                        skipf[(size_t)grow * HIDDEN + (gcol - 768)] = vres;
                    }
                }
            }
        }
    }
}

// ---------------------------------------------------------------------------
// TransformerConv aggregation v3: one wave per dst node, half-wave per edge,
// k/v in fp8 interleaved 8-dim chunks -> ONE uint4 load per lane per edge.
// sl = lane&31 owns dims [8*sl, 8*sl+8); head = sl>>3; dot-reduce shfl 1,2,4.
// ---------------------------------------------------------------------------
__device__ __forceinline__ void edge_step(uint4 kv, const float* qf,
                                          float& z, float* ac) {
    floatx2 k01 = __builtin_amdgcn_cvt_pk_f32_fp8(kv.x, false);
    floatx2 k23 = __builtin_amdgcn_cvt_pk_f32_fp8(kv.x, true);
    floatx2 k45 = __builtin_amdgcn_cvt_pk_f32_fp8(kv.y, false);
    floatx2 k67 = __builtin_amdgcn_cvt_pk_f32_fp8(kv.y, true);
    float d = qf[0] * k01[0] + qf[1] * k01[1] + qf[2] * k23[0] + qf[3] * k23[1]
            + qf[4] * k45[0] + qf[5] * k45[1] + qf[6] * k67[0] + qf[7] * k67[1];
    d += __shfl_xor(d, 1);
    d += __shfl_xor(d, 2);
    d += __shfl_xor(d, 4);
    float p = __expf(d * 0.125f);
    z += p;
    floatx2 v01 = __builtin_amdgcn_cvt_pk_f32_fp8(kv.z, false);
    floatx2 v23 = __builtin_amdgcn_cvt_pk_f32_fp8(kv.z, true);
    floatx2 v45 = __builtin_amdgcn_cvt_pk_f32_fp8(kv.w, false);
    floatx2 v67 = __builtin_amdgcn_cvt_pk_f32_fp8(kv.w, true);
    ac[0] = fmaf(p, v01[0], ac[0]); ac[1] = fmaf(p, v01[1], ac[1]);
    ac[2] = fmaf(p, v23[0], ac[2]); ac[3] = fmaf(p, v23[1], ac[3]);
    ac[4] = fmaf(p, v45[0], ac[4]); ac[5] = fmaf(p, v45[1], ac[5]);
    ac[6] = fmaf(p, v67[0], ac[6]); ac[7] = fmaf(p, v67[1], ac[7]);
}

template <bool OUT_BF16>
__global__ __launch_bounds__(256) void attn_agg3(const ushort_t* __restrict__ qb,
                                                 const uchar_t* __restrict__ kvb,
                                                 const float* __restrict__ skipf,
                                                 const int* __restrict__ rowptr,
                                                 const int* __restrict__ col,
                                                 void* __restrict__ hout) {
    int node = blockIdx.x * 4 + threadIdx.y;
    if (node >= N_NODES) return;
    int lane = threadIdx.x;
    int half = lane >> 5, sl = lane & 31;
    // q dims [8sl, 8sl+8) as 8 floats
    uint4 qu = *(const uint4*)(qb + (size_t)node * 256 + sl * 8);
    float4 qa = bf4_unpack(qu.x, qu.y);
    float4 qc = bf4_unpack(qu.z, qu.w);
    float qf[8] = {qa.x, qa.y, qa.z, qa.w, qc.x, qc.y, qc.z, qc.w};
    float ac[8] = {0.f, 0.f, 0.f, 0.f, 0.f, 0.f, 0.f, 0.f};
    float z = 0.f;
    int beg = rowptr[node], end = rowptr[node + 1];
    int e = beg + half;
    const size_t loff = (size_t)sl * 16;
    // 4 edges per half in flight (8 per wave)
    for (; e + 6 < end; e += 8) {
        int s0 = col[e], s1 = col[e + 2], s2 = col[e + 4], s3 = col[e + 6];
        uint4 kv0 = *(const uint4*)(kvb + (size_t)s0 * 512 + loff);
        uint4 kv1 = *(const uint4*)(kvb + (size_t)s1 * 512 + loff);
        uint4 kv2 = *(const uint4*)(kvb + (size_t)s2 * 512 + loff);
        uint4 kv3 = *(const uint4*)(kvb + (size_t)s3 * 512 + loff);
        edge_step(kv0, qf, z, ac);
        edge_step(kv1, qf, z, ac);
        edge_step(kv2, qf, z, ac);
        edge_step(kv3, qf, z, ac);
    }
    for (; e < end; e += 2) {
        uint4 kv0 = *(const uint4*)(kvb + (size_t)col[e] * 512 + loff);
        edge_step(kv0, qf, z, ac);
    }
    // combine the two halves
    z += __shfl_xor(z, 32);
#pragma unroll
    for (int i = 0; i < 8; ++i) ac[i] += __shfl_xor(ac[i], 32);
    float inv = (z > 0.f) ? (1.f / z) : 0.f;
#pragma unroll
    for (int i = 0; i < 8; ++i) ac[i] *= inv;
    // head mean: lanes {sl, sl^8, sl^16, sl^24} hold same within-head dims
#pragma unroll
    for (int i = 0; i < 8; ++i) {
        ac[i] += __shfl_xor(ac[i], 8);
        ac[i] += __shfl_xor(ac[i], 16);
    }
    if (lane < 8) {   // lane holds output dims [8*lane, 8*lane+8)
        const float* sp = skipf + (size_t)node * HIDDEN + lane * 8;
        float4 s0 = *(const float4*)(sp);
        float4 s1 = *(const float4*)(sp + 4);
        float o0 = fmaxf(ac[0] * 0.25f + s0.x, 0.f);
        float o1 = fmaxf(ac[1] * 0.25f + s0.y, 0.f);
        float o2 = fmaxf(ac[2] * 0.25f + s0.z, 0.f);
        float o3 = fmaxf(ac[3] * 0.25f + s0.w, 0.f);
        float o4 = fmaxf(ac[4] * 0.25f + s1.x, 0.f);
        float o5 = fmaxf(ac[5] * 0.25f + s1.y, 0.f);
        float o6 = fmaxf(ac[6] * 0.25f + s1.z, 0.f);
        float o7 = fmaxf(ac[7] * 0.25f + s1.w, 0.f);
        if (OUT_BF16) {
            uint4 u;
            u.x = (uint_t)bf16rne(o0) | ((uint_t)bf16rne(o1) << 16);
            u.y = (uint_t)bf16rne(o2) | ((uint_t)bf16rne(o3) << 16);
            u.z = (uint_t)bf16rne(o4) | ((uint_t)bf16rne(o5) << 16);
            u.w = (uint_t)bf16rne(o6) | ((uint_t)bf16rne(o7) << 16);
            *(uint4*)((ushort_t*)hout + (size_t)node * HIDDEN + lane * 8) = u;
        } else {
            float* op = (float*)hout + (size_t)node * HIDDEN + lane * 8;
            *(float4*)(op)     = make_float4(o0, o1, o2, o3);
            *(float4*)(op + 4) = make_float4(o4, o5, o6, o7);
        }
    }
}

// ---------------------------------------------------------------------------
// Per-graph mean pool (batch is sorted -> binary search boundaries, no atomics)
// ---------------------------------------------------------------------------
__global__ void pool_mean(const float* __restrict__ h, const int* __restrict__ batch,
                          float* __restrict__ gsum, int* __restrict__ gcnt) {
    int g = blockIdx.x;
    int lo = 0, hi = N_NODES;
    while (lo < hi) { int mid = (lo + hi) >> 1; if (batch[mid] < g) lo = mid + 1; else hi = mid; }
    int start = lo;
    hi = N_NODES;
    while (lo < hi) { int mid = (lo + hi) >> 1; if (batch[mid] < g + 1) lo = mid + 1; else hi = mid; }
    int end = lo;
    int t = threadIdx.x;
    int d = t & 63, chunk = t >> 6;   // 256 threads: 4 chunks x 64 dims
    float acc = 0.f;
    for (int n = start + chunk; n < end; n += 4) acc += h[(size_t)n * HIDDEN + d];
    __shared__ float sh[256];
    sh[t] = acc;
    __syncthreads();
    if (chunk == 0) {
        gsum[g * HIDDEN + d] = sh[d] + sh[64 + d] + sh[128 + d] + sh[192 + d];
        if (d == 0) gcnt[g] = end - start;
    }
}

// ---------------------------------------------------------------------------
// Final MLP head: one block (64 threads) per graph
// ---------------------------------------------------------------------------
__global__ __launch_bounds__(64) void mlp_head(const float* __restrict__ gsum,
                                               const int* __restrict__ gcnt,
                                               const float* __restrict__ gf,
                                               const float* __restrict__ gW1, const float* __restrict__ gb1,
                                               const float* __restrict__ gW2, const float* __restrict__ gb2,
                                               const float* __restrict__ hW1, const float* __restrict__ hb1,
                                               const float* __restrict__ hW2, const float* __restrict__ hb2,
                                               float* __restrict__ out) {
    int g = blockIdx.x;
    int t = threadIdx.x;   // 64 threads
    __shared__ float gfs[GLOBAL_DIM];
    __shared__ float g1[HIDDEN];
    __shared__ float fused[2 * HIDDEN];
    __shared__ float h1s[HIDDEN];
    for (int i = t; i < GLOBAL_DIM; i += 64) gfs[i] = gf[(size_t)g * GLOBAL_DIM + i];
    float cnt = (float)gcnt[g];
    cnt = fmaxf(cnt, 1.0f);
    fused[t] = gsum[g * HIDDEN + t] / cnt;   // patch_emb
    __syncthreads();
    float acc = gb1[t];
    for (int k = 0; k < GLOBAL_DIM; ++k) acc = fmaf(gfs[k], gW1[k * HIDDEN + t], acc);
    g1[t] = fmaxf(acc, 0.f);
    __syncthreads();
    acc = gb2[t];
    for (int k = 0; k < HIDDEN; ++k) acc = fmaf(g1[k], gW2[k * HIDDEN + t], acc);
    fused[HIDDEN + t] = fmaxf(acc, 0.f);
    __syncthreads();
    acc = hb1[t];
    for (int k = 0; k < 2 * HIDDEN; ++k) acc = fmaf(fused[k], hW1[k * HIDDEN + t], acc);
    h1s[t] = fmaxf(acc, 0.f);
    __syncthreads();
    if (t < N_CLASSES) {
        float o = hb2[t];
        for (int k = 0; k < HIDDEN; ++k) o = fmaf(h1s[k], hW2[k * N_CLASSES + t], o);
        out[(size_t)g * N_CLASSES + t] = o;
    }
}

// ---------------------------------------------------------------------------
extern "C" void kernel_launch(void* const* d_in, const int* in_sizes, int n_in,
                              void* d_out, int out_size, void* d_ws, size_t ws_size,
                              hipStream_t stream) {
    const float* x        = (const float*)d_in[0];
    const int*   eidx     = (const int*)d_in[1];
    const int*   batch    = (const int*)d_in[2];
    const float* gfeats   = (const float*)d_in[3];
    const float* c1_Wq = (const float*)d_in[4];  const float* c1_bq = (const float*)d_in[5];
    const float* c1_Wk = (const float*)d_in[6];  const float* c1_bk = (const float*)d_in[7];
    const float* c1_Wv = (const float*)d_in[8];  const float* c1_bv = (const float*)d_in[9];
    const float* c1_Ws = (const float*)d_in[10]; const float* c1_bs = (const float*)d_in[11];
    const float* c2_Wq = (const float*)d_in[12]; const float* c2_bq = (const float*)d_in[13];
    const float* c2_Wk = (const float*)d_in[14]; const float* c2_bk = (const float*)d_in[15];
    const float* c2_Wv = (const float*)d_in[16]; const float* c2_bv = (const float*)d_in[17];
    const float* c2_Ws = (const float*)d_in[18]; const float* c2_bs = (const float*)d_in[19];
    const float* g_W1 = (const float*)d_in[20]; const float* g_b1 = (const float*)d_in[21];
    const float* g_W2 = (const float*)d_in[22]; const float* g_b2 = (const float*)d_in[23];
    const float* h_W1 = (const float*)d_in[24]; const float* h_b1 = (const float*)d_in[25];
    const float* h_W2 = (const float*)d_in[26]; const float* h_b2 = (const float*)d_in[27];
    float* out = (float*)d_out;

    const int* srcp = eidx;
    const int* dstp = eidx + N_EDGES;

    // ---- workspace layout (all region sizes multiples of 16 B) ----
    char* base = (char*)d_ws;
    uchar_t*  kvb  = (uchar_t*)base;  base += (size_t)N_NODES * 512;         // 25.6 MB
    ushort_t* qb   = (ushort_t*)base; base += (size_t)N_NODES * 256 * 2;     // 25.6 MB
    float*    skipf = (float*)base;   base += (size_t)N_NODES * HIDDEN * 4;  // 12.8 MB
    ushort_t* h1b  = (ushort_t*)base; base += (size_t)N_NODES * HIDDEN * 2;  //  6.4 MB
    float*    h2   = (float*)base;    base += (size_t)N_NODES * HIDDEN * 4;  // 12.8 MB
    ushort_t* Wt   = (ushort_t*)base; base += (size_t)IN_CH * QKV_COLS * 2;  // 213 KB (max K)
    float*    bcat = (float*)base;    base += QKV_COLS * 4;
    float*    gsum = (float*)base;    base += N_GRAPHS * HIDDEN * 4;
    int* ib = (int*)base;
    size_t oi = 0;
    int* deg    = ib + oi; oi += N_NODES;
    int* incl   = ib + oi; oi += N_NODES;
    int* bsums  = ib + oi; oi += 64;
    int* boff   = ib + oi; oi += 64;
    int* rowptr = ib + oi; oi += N_NODES + 4;
    int* cur    = ib + oi; oi += N_NODES;
    int* colb   = ib + oi; oi += N_EDGES;
    int* gcnt   = ib + oi; oi += 64;

    const int NB1 = (N_NODES + 1023) / 1024;   // 49
    const int EB  = (N_EDGES + 255) / 256;     // 3125
    const int NBS = (N_NODES + 255) / 256;     // 196

    // ---- CSR build (shared by both conv layers) ----
    hipMemsetAsync(deg, 0, N_NODES * sizeof(int), stream);
    count_deg<<<EB, 256, 0, stream>>>(dstp, deg);
    scan1<<<NB1, 1024, 0, stream>>>(deg, incl, bsums, N_NODES);
    scan2<<<1, 64, 0, stream>>>(bsums, boff, NB1);
    scan3<<<NBS, 256, 0, stream>>>(deg, incl, boff, rowptr, cur, N_NODES);
    fill_col<<<EB, 256, 0, stream>>>(srcp, dstp, cur, colb);

    int gemm_grid = (N_NODES + 127) / 128;     // 391
    dim3 attn_block(64, 4);
    int attn_grid = (N_NODES + 3) / 4;         // 12500

    // ---- conv1 (A = x fp32, cast during LDS staging) ----
    concat_w_t<<<(IN_CH * QKV_COLS + 255) / 256, 256, 0, stream>>>(
        c1_Wq, c1_Wk, c1_Wv, c1_Ws, c1_bq, c1_bk, c1_bv, c1_bs, Wt, bcat, IN_CH);
    gemm_mfma3<IN_CH, true><<<gemm_grid, 256, 0, stream>>>(x, Wt, bcat, qb, kvb, skipf, N_NODES);
    attn_agg3<true><<<attn_grid, attn_block, 0, stream>>>(qb, kvb, skipf, rowptr, colb, h1b);

    // ---- conv2 (A = h1b bf16; reuses qb/kvb/skipf buffers) ----
    concat_w_t<<<(HIDDEN * QKV_COLS + 255) / 256, 256, 0, stream>>>(
        c2_Wq, c2_Wk, c2_Wv, c2_Ws, c2_bq, c2_bk, c2_bv, c2_bs, Wt, bcat, HIDDEN);
    gemm_mfma3<HIDDEN, false><<<gemm_grid, 256, 0, stream>>>(h1b, Wt, bcat, qb, kvb, skipf, N_NODES);
    attn_agg3<false><<<attn_grid, attn_block, 0, stream>>>(qb, kvb, skipf, rowptr, colb, h2);

    // ---- pool + head ----
    pool_mean<<<N_GRAPHS, 256, 0, stream>>>(h2, batch, gsum, gcnt);
    mlp_head<<<N_GRAPHS, 64, 0, stream>>>(gsum, gcnt, gfeats,
                                          g_W1, g_b1, g_W2, g_b2,
                                          h_W1, h_b1, h_W2, h_b2, out);
}

// Round 5
// 508.396 us; speedup vs baseline: 2.0027x; 1.1161x over previous
//
#include <hip/hip_runtime.h>
#include <hip/hip_bf16.h>
#include <math.h>

#define N_NODES   50000
#define N_EDGES   800000
#define N_GRAPHS  64
#define IN_CH     128
#define GLOBAL_DIM 256
#define HIDDEN    64
#define HEADS     4
#define N_CLASSES 10
#define QKV_COLS  832   // 256 q | 256 k | 256 v | 64 skip

typedef unsigned short ushort_t;
typedef unsigned int uint_t;
typedef unsigned char uchar_t;
typedef __attribute__((ext_vector_type(8))) short short8;
typedef __attribute__((ext_vector_type(4))) float floatx4;
typedef __attribute__((ext_vector_type(2))) float floatx2;

// ---------------------------------------------------------------------------
// helpers
// ---------------------------------------------------------------------------
__device__ __forceinline__ ushort_t bf16rne(float f) {
    uint_t b = __float_as_uint(f);
    b += 0x7fffu + ((b >> 16) & 1u);
    return (ushort_t)(b >> 16);
}
__device__ __forceinline__ float4 bf4_unpack(uint_t lo, uint_t hi) {
    float4 f;
    f.x = __uint_as_float(lo << 16);
    f.y = __uint_as_float(lo & 0xffff0000u);
    f.z = __uint_as_float(hi << 16);
    f.w = __uint_as_float(hi & 0xffff0000u);
    return f;
}
__device__ __forceinline__ uchar_t fp8e4m3(float f) {
    int v = __builtin_amdgcn_cvt_pk_fp8_f32(f, 0.f, 0, false);
    return (uchar_t)(v & 0xff);
}

// ---------------------------------------------------------------------------
// CSR build: deg -> inclusive scan -> rowptr/cursor -> fill col (src ids)
// ---------------------------------------------------------------------------
__global__ void count_deg(const int* __restrict__ dst, int* __restrict__ deg) {
    int e = blockIdx.x * 256 + threadIdx.x;
    if (e < N_EDGES) atomicAdd(&deg[dst[e]], 1);
}

__global__ void scan1(const int* __restrict__ deg, int* __restrict__ incl,
                      int* __restrict__ bsums, int n) {
    __shared__ int sh[1024];
    int t = threadIdx.x;
    int gid = blockIdx.x * 1024 + t;
    int v = (gid < n) ? deg[gid] : 0;
    sh[t] = v;
    __syncthreads();
    for (int off = 1; off < 1024; off <<= 1) {
        int tmp = (t >= off) ? sh[t - off] : 0;
        __syncthreads();
        sh[t] += tmp;
        __syncthreads();
    }
    if (gid < n) incl[gid] = sh[t];
    if (t == 1023) bsums[blockIdx.x] = sh[1023];
}

__global__ void scan2(const int* __restrict__ bsums, int* __restrict__ boff, int nb) {
    int t = threadIdx.x;   // 64 threads, nb <= 64
    int v = (t < nb) ? bsums[t] : 0;
    int incl = v;
#pragma unroll
    for (int off = 1; off < 64; off <<= 1) {
        int u = __shfl_up(incl, off);
        if (t >= off) incl += u;
    }
    if (t < nb) boff[t] = incl - v;   // exclusive
}

__global__ void scan3(const int* __restrict__ deg, const int* __restrict__ incl,
                      const int* __restrict__ boff, int* __restrict__ rowptr,
                      int* __restrict__ cur, int n) {
    int gid = blockIdx.x * 256 + threadIdx.x;
    if (gid < n) {
        int b = gid >> 10;
        int in = incl[gid] + boff[b];
        int ex = in - deg[gid];
        rowptr[gid] = ex;
        cur[gid] = ex;
        if (gid == n - 1) rowptr[n] = in;
    }
}

__global__ void fill_col(const int* __restrict__ src, const int* __restrict__ dst,
                         int* __restrict__ cur, int* __restrict__ col) {
    int e = blockIdx.x * 256 + threadIdx.x;
    if (e < N_EDGES) {
        int d = dst[e];
        int pos = atomicAdd(&cur[d], 1);
        col[pos] = src[e];
    }
}

// ---------------------------------------------------------------------------
// Concatenate + transpose weights: Wt[c][k] (bf16), c in [0,832), plus bcat fp32
// ---------------------------------------------------------------------------
__global__ void concat_w_t(const float* __restrict__ Wq, const float* __restrict__ Wk,
                           const float* __restrict__ Wv, const float* __restrict__ Ws,
                           const float* __restrict__ bq, const float* __restrict__ bk,
                           const float* __restrict__ bv, const float* __restrict__ bs,
                           ushort_t* __restrict__ Wt, float* __restrict__ bcat, int K) {
    int idx = blockIdx.x * 256 + threadIdx.x;
    int total = K * QKV_COLS;
    if (idx < total) {
        int c = idx / K, k = idx % K;
        float v;
        if (c < 256)      v = Wq[k * 256 + c];
        else if (c < 512) v = Wk[k * 256 + (c - 256)];
        else if (c < 768) v = Wv[k * 256 + (c - 512)];
        else              v = Ws[k * 64  + (c - 768)];
        Wt[idx] = bf16rne(v);
    }
    if (idx < QKV_COLS) {
        float b;
        if (idx < 256)      b = bq[idx];
        else if (idx < 512) b = bk[idx - 256];
        else if (idx < 768) b = bv[idx - 512];
        else                b = bs[idx - 768];
        bcat[idx] = b;
    }
}

// ---------------------------------------------------------------------------
// bf16 MFMA GEMM v4: one 64-col tile per block, grid (13 col, ceil(N/128) row).
// blockIdx.x fastest -> 13 blocks sharing an A strip dispatch adjacently (L2).
// Epilogue: stage output tile in LDS (reuse As), then coalesced wide stores.
// Outputs: ct 0-3  -> qb bf16 [N,256]
//          ct 4-7  -> kvb fp8 k-halves: byte 16*(c>>3)+(c&7)
//          ct 8-11 -> kvb fp8 v-halves: byte 16*(c>>3)+8+(c&7)
//          ct 12   -> skipf fp32 [N,64]
// ---------------------------------------------------------------------------
template <int K, bool A_FP32>
__global__ __launch_bounds__(256) void gemm_v4(const void* __restrict__ Av,
                                               const ushort_t* __restrict__ Wt,
                                               const float* __restrict__ bias,
                                               ushort_t* __restrict__ qb,
                                               uchar_t* __restrict__ kvb,
                                               float* __restrict__ skipf, int N) {
    constexpr int KP = K + 8;      // padded LDS row stride (bf16 units)
    constexpr int C8 = K / 8;      // 16B bf16 chunks per row
    __shared__ ushort_t As[128 * KP] __attribute__((aligned(16)));
    __shared__ ushort_t Bs[64 * KP] __attribute__((aligned(16)));

    const int t = threadIdx.x;
    const int ct = blockIdx.x;            // 0..12
    const int base_r = blockIdx.y * 128;
    const int base_c = ct * 64;

    // ---- stage A tile (128 x K) ----
    if (A_FP32) {
        const float* A = (const float*)Av;
        constexpr int C4 = K / 4;
#pragma unroll
        for (int i = 0; i < (128 * C4) / 256; ++i) {
            int idx = t + i * 256;
            int r = idx / C4, c = idx % C4;
            int gr = base_r + r;
            float4 av = make_float4(0.f, 0.f, 0.f, 0.f);
            if (gr < N) av = *(const float4*)(A + (size_t)gr * K + c * 4);
            uint2 u;
            u.x = (uint_t)bf16rne(av.x) | ((uint_t)bf16rne(av.y) << 16);
            u.y = (uint_t)bf16rne(av.z) | ((uint_t)bf16rne(av.w) << 16);
            *(uint2*)(As + r * KP + c * 4) = u;
        }
    } else {
        const ushort_t* A = (const ushort_t*)Av;
#pragma unroll
        for (int i = 0; i < (128 * C8) / 256; ++i) {
            int idx = t + i * 256;
            int r = idx / C8, c = idx % C8;
            int gr = base_r + r;
            uint4 val = make_uint4(0u, 0u, 0u, 0u);
            if (gr < N) val = *(const uint4*)(A + (size_t)gr * K + c * 8);
            *(uint4*)(As + r * KP + c * 8) = val;
        }
    }
    // ---- stage B tile (64 cols of Wt) ----
#pragma unroll
    for (int i = 0; i < (64 * C8) / 256; ++i) {
        int idx = t + i * 256;
        int n = idx / C8, c = idx % C8;
        *(uint4*)(Bs + n * KP + c * 8) =
            *(const uint4*)(Wt + (size_t)(base_c + n) * K + c * 8);
    }
    __syncthreads();

    const int wave = t >> 6, lane = t & 63;
    const int quad = lane >> 4, m16 = lane & 15;

    floatx4 acc[2][4];
#pragma unroll
    for (int rt = 0; rt < 2; ++rt)
#pragma unroll
        for (int c2 = 0; c2 < 4; ++c2) acc[rt][c2] = (floatx4){0.f, 0.f, 0.f, 0.f};
#pragma unroll
    for (int kc = 0; kc < K / 32; ++kc) {
        int ko = kc * 32 + quad * 8;
        short8 a0 = *(const short8*)(As + (wave * 32 + m16) * KP + ko);
        short8 a1 = *(const short8*)(As + (wave * 32 + 16 + m16) * KP + ko);
#pragma unroll
        for (int c2 = 0; c2 < 4; ++c2) {
            short8 b = *(const short8*)(Bs + (c2 * 16 + m16) * KP + ko);
            acc[0][c2] = __builtin_amdgcn_mfma_f32_16x16x32_bf16(a0, b, acc[0][c2], 0, 0, 0);
            acc[1][c2] = __builtin_amdgcn_mfma_f32_16x16x32_bf16(a1, b, acc[1][c2], 0, 0, 0);
        }
    }

    // add bias in-register
    float bb[4];
#pragma unroll
    for (int c2 = 0; c2 < 4; ++c2) bb[c2] = bias[base_c + c2 * 16 + m16];
#pragma unroll
    for (int rt = 0; rt < 2; ++rt)
#pragma unroll
        for (int c2 = 0; c2 < 4; ++c2)
#pragma unroll
            for (int r = 0; r < 4; ++r) acc[rt][c2][r] += bb[c2];

    __syncthreads();   // all waves done reading As/Bs; reuse As for epilogue

    // lane's element (rt,c2,r): row_l = wave*32+rt*16+quad*4+r, col_l = c2*16+m16
    if (ct < 4) {
        // ---- q tile: bf16 [128][64] in LDS, then 16B stores ----
        ushort_t* ep = As;
#pragma unroll
        for (int c2 = 0; c2 < 4; ++c2) {
            int col_l = c2 * 16 + m16;
#pragma unroll
            for (int rt = 0; rt < 2; ++rt)
#pragma unroll
                for (int r = 0; r < 4; ++r)
                    ep[(wave * 32 + rt * 16 + quad * 4 + r) * 64 + col_l] =
                        bf16rne(acc[rt][c2][r]);
        }
        __syncthreads();
#pragma unroll
        for (int i = 0; i < 4; ++i) {
            int idx = t + i * 256;
            int row = idx >> 3, ch = idx & 7;
            int gr = base_r + row;
            if (gr < N)
                *(uint4*)(qb + (size_t)gr * 256 + base_c + ch * 8) =
                    *(const uint4*)(ep + row * 64 + ch * 8);
        }
    } else if (ct < 12) {
        // ---- k/v tile: fp8 [128][64] bytes in LDS, then 8B stores ----
        const bool isv = (ct >= 8);
        uchar_t* ep = (uchar_t*)As;
#pragma unroll
        for (int c2 = 0; c2 < 4; ++c2) {
            int col_l = c2 * 16 + m16;
#pragma unroll
            for (int rt = 0; rt < 2; ++rt)
#pragma unroll
                for (int r = 0; r < 4; ++r)
                    ep[(wave * 32 + rt * 16 + quad * 4 + r) * 64 + col_l] =
                        fp8e4m3(acc[rt][c2][r]);
        }
        __syncthreads();
        const int j0 = (base_c - (isv ? 512 : 256)) >> 3;   // global 8-dim chunk base
        const int sub = isv ? 8 : 0;
#pragma unroll
        for (int i = 0; i < 4; ++i) {
            int idx = t + i * 256;
            int row = idx >> 3, jj = idx & 7;
            int gr = base_r + row;
            if (gr < N)
                *(uint2*)(kvb + (size_t)gr * 512 + 16 * (j0 + jj) + sub) =
                    *(const uint2*)(ep + row * 64 + jj * 8);
        }
    } else {
        // ---- skip tile: fp32, two 64-row passes through LDS (16 KB) ----
        float* ep = (float*)As;
#pragma unroll
        for (int p = 0; p < 2; ++p) {
            if ((wave >> 1) == p) {
#pragma unroll
                for (int c2 = 0; c2 < 4; ++c2) {
                    int col_l = c2 * 16 + m16;
#pragma unroll
                    for (int rt = 0; rt < 2; ++rt)
#pragma unroll
                        for (int r = 0; r < 4; ++r)
                            ep[((wave & 1) * 32 + rt * 16 + quad * 4 + r) * 64 + col_l] =
                                acc[rt][c2][r];
                }
            }
            __syncthreads();
#pragma unroll
            for (int i = 0; i < 4; ++i) {
                int idx = t + i * 256;
                int row = idx >> 4, ch = idx & 15;
                int gr = base_r + p * 64 + row;
                if (gr < N)
                    *(float4*)(skipf + (size_t)gr * HIDDEN + ch * 4) =
                        *(const float4*)(ep + row * 64 + ch * 4);
            }
            __syncthreads();
        }
    }
}

// ---------------------------------------------------------------------------
// TransformerConv aggregation v3: one wave per dst node, half-wave per edge,
// k/v in fp8 interleaved 8-dim chunks -> ONE uint4 load per lane per edge.
// sl = lane&31 owns dims [8*sl, 8*sl+8); head = sl>>3; dot-reduce shfl 1,2,4.
// ---------------------------------------------------------------------------
__device__ __forceinline__ void edge_step(uint4 kv, const float* qf,
                                          float& z, float* ac) {
    floatx2 k01 = __builtin_amdgcn_cvt_pk_f32_fp8(kv.x, false);
    floatx2 k23 = __builtin_amdgcn_cvt_pk_f32_fp8(kv.x, true);
    floatx2 k45 = __builtin_amdgcn_cvt_pk_f32_fp8(kv.y, false);
    floatx2 k67 = __builtin_amdgcn_cvt_pk_f32_fp8(kv.y, true);
    float d = qf[0] * k01[0] + qf[1] * k01[1] + qf[2] * k23[0] + qf[3] * k23[1]
            + qf[4] * k45[0] + qf[5] * k45[1] + qf[6] * k67[0] + qf[7] * k67[1];
    d += __shfl_xor(d, 1);
    d += __shfl_xor(d, 2);
    d += __shfl_xor(d, 4);
    float p = __expf(d * 0.125f);
    z += p;
    floatx2 v01 = __builtin_amdgcn_cvt_pk_f32_fp8(kv.z, false);
    floatx2 v23 = __builtin_amdgcn_cvt_pk_f32_fp8(kv.z, true);
    floatx2 v45 = __builtin_amdgcn_cvt_pk_f32_fp8(kv.w, false);
    floatx2 v67 = __builtin_amdgcn_cvt_pk_f32_fp8(kv.w, true);
    ac[0] = fmaf(p, v01[0], ac[0]); ac[1] = fmaf(p, v01[1], ac[1]);
    ac[2] = fmaf(p, v23[0], ac[2]); ac[3] = fmaf(p, v23[1], ac[3]);
    ac[4] = fmaf(p, v45[0], ac[4]); ac[5] = fmaf(p, v45[1], ac[5]);
    ac[6] = fmaf(p, v67[0], ac[6]); ac[7] = fmaf(p, v67[1], ac[7]);
}

template <bool OUT_BF16>
__global__ __launch_bounds__(256) void attn_agg3(const ushort_t* __restrict__ qb,
                                                 const uchar_t* __restrict__ kvb,
                                                 const float* __restrict__ skipf,
                                                 const int* __restrict__ rowptr,
                                                 const int* __restrict__ col,
                                                 void* __restrict__ hout) {
    int node = blockIdx.x * 4 + threadIdx.y;
    if (node >= N_NODES) return;
    int lane = threadIdx.x;
    int half = lane >> 5, sl = lane & 31;
    uint4 qu = *(const uint4*)(qb + (size_t)node * 256 + sl * 8);
    float4 qa = bf4_unpack(qu.x, qu.y);
    float4 qc = bf4_unpack(qu.z, qu.w);
    float qf[8] = {qa.x, qa.y, qa.z, qa.w, qc.x, qc.y, qc.z, qc.w};
    float ac[8] = {0.f, 0.f, 0.f, 0.f, 0.f, 0.f, 0.f, 0.f};
    float z = 0.f;
    int beg = rowptr[node], end = rowptr[node + 1];
    int e = beg + half;
    const size_t loff = (size_t)sl * 16;
    for (; e + 6 < end; e += 8) {
        int s0 = col[e], s1 = col[e + 2], s2 = col[e + 4], s3 = col[e + 6];
        uint4 kv0 = *(const uint4*)(kvb + (size_t)s0 * 512 + loff);
        uint4 kv1 = *(const uint4*)(kvb + (size_t)s1 * 512 + loff);
        uint4 kv2 = *(const uint4*)(kvb + (size_t)s2 * 512 + loff);
        uint4 kv3 = *(const uint4*)(kvb + (size_t)s3 * 512 + loff);
        edge_step(kv0, qf, z, ac);
        edge_step(kv1, qf, z, ac);
        edge_step(kv2, qf, z, ac);
        edge_step(kv3, qf, z, ac);
    }
    for (; e < end; e += 2) {
        uint4 kv0 = *(const uint4*)(kvb + (size_t)col[e] * 512 + loff);
        edge_step(kv0, qf, z, ac);
    }
    z += __shfl_xor(z, 32);
#pragma unroll
    for (int i = 0; i < 8; ++i) ac[i] += __shfl_xor(ac[i], 32);
    float inv = (z > 0.f) ? (1.f / z) : 0.f;
#pragma unroll
    for (int i = 0; i < 8; ++i) ac[i] *= inv;
#pragma unroll
    for (int i = 0; i < 8; ++i) {
        ac[i] += __shfl_xor(ac[i], 8);
        ac[i] += __shfl_xor(ac[i], 16);
    }
    if (lane < 8) {   // lane holds output dims [8*lane, 8*lane+8)
        const float* sp = skipf + (size_t)node * HIDDEN + lane * 8;
        float4 s0 = *(const float4*)(sp);
        float4 s1 = *(const float4*)(sp + 4);
        float o0 = fmaxf(ac[0] * 0.25f + s0.x, 0.f);
        float o1 = fmaxf(ac[1] * 0.25f + s0.y, 0.f);
        float o2 = fmaxf(ac[2] * 0.25f + s0.z, 0.f);
        float o3 = fmaxf(ac[3] * 0.25f + s0.w, 0.f);
        float o4 = fmaxf(ac[4] * 0.25f + s1.x, 0.f);
        float o5 = fmaxf(ac[5] * 0.25f + s1.y, 0.f);
        float o6 = fmaxf(ac[6] * 0.25f + s1.z, 0.f);
        float o7 = fmaxf(ac[7] * 0.25f + s1.w, 0.f);
        if (OUT_BF16) {
            uint4 u;
            u.x = (uint_t)bf16rne(o0) | ((uint_t)bf16rne(o1) << 16);
            u.y = (uint_t)bf16rne(o2) | ((uint_t)bf16rne(o3) << 16);
            u.z = (uint_t)bf16rne(o4) | ((uint_t)bf16rne(o5) << 16);
            u.w = (uint_t)bf16rne(o6) | ((uint_t)bf16rne(o7) << 16);
            *(uint4*)((ushort_t*)hout + (size_t)node * HIDDEN + lane * 8) = u;
        } else {
            float* op = (float*)hout + (size_t)node * HIDDEN + lane * 8;
            *(float4*)(op)     = make_float4(o0, o1, o2, o3);
            *(float4*)(op + 4) = make_float4(o4, o5, o6, o7);
        }
    }
}

// ---------------------------------------------------------------------------
// Per-graph mean pool (batch is sorted -> binary search boundaries, no atomics)
// ---------------------------------------------------------------------------
__global__ void pool_mean(const float* __restrict__ h, const int* __restrict__ batch,
                          float* __restrict__ gsum, int* __restrict__ gcnt) {
    int g = blockIdx.x;
    int lo = 0, hi = N_NODES;
    while (lo < hi) { int mid = (lo + hi) >> 1; if (batch[mid] < g) lo = mid + 1; else hi = mid; }
    int start = lo;
    hi = N_NODES;
    while (lo < hi) { int mid = (lo + hi) >> 1; if (batch[mid] < g + 1) lo = mid + 1; else hi = mid; }
    int end = lo;
    int t = threadIdx.x;
    int d = t & 63, chunk = t >> 6;   // 256 threads: 4 chunks x 64 dims
    float acc = 0.f;
    for (int n = start + chunk; n < end; n += 4) acc += h[(size_t)n * HIDDEN + d];
    __shared__ float sh[256];
    sh[t] = acc;
    __syncthreads();
    if (chunk == 0) {
        gsum[g * HIDDEN + d] = sh[d] + sh[64 + d] + sh[128 + d] + sh[192 + d];
        if (d == 0) gcnt[g] = end - start;
    }
}

// ---------------------------------------------------------------------------
// Final MLP head: one block (64 threads) per graph
// ---------------------------------------------------------------------------
__global__ __launch_bounds__(64) void mlp_head(const float* __restrict__ gsum,
                                               const int* __restrict__ gcnt,
                                               const float* __restrict__ gf,
                                               const float* __restrict__ gW1, const float* __restrict__ gb1,
                                               const float* __restrict__ gW2, const float* __restrict__ gb2,
                                               const float* __restrict__ hW1, const float* __restrict__ hb1,
                                               const float* __restrict__ hW2, const float* __restrict__ hb2,
                                               float* __restrict__ out) {
    int g = blockIdx.x;
    int t = threadIdx.x;   // 64 threads
    __shared__ float gfs[GLOBAL_DIM];
    __shared__ float g1[HIDDEN];
    __shared__ float fused[2 * HIDDEN];
    __shared__ float h1s[HIDDEN];
    for (int i = t; i < GLOBAL_DIM; i += 64) gfs[i] = gf[(size_t)g * GLOBAL_DIM + i];
    float cnt = (float)gcnt[g];
    cnt = fmaxf(cnt, 1.0f);
    fused[t] = gsum[g * HIDDEN + t] / cnt;   // patch_emb
    __syncthreads();
    float acc = gb1[t];
    for (int k = 0; k < GLOBAL_DIM; ++k) acc = fmaf(gfs[k], gW1[k * HIDDEN + t], acc);
    g1[t] = fmaxf(acc, 0.f);
    __syncthreads();
    acc = gb2[t];
    for (int k = 0; k < HIDDEN; ++k) acc = fmaf(g1[k], gW2[k * HIDDEN + t], acc);
    fused[HIDDEN + t] = fmaxf(acc, 0.f);
    __syncthreads();
    acc = hb1[t];
    for (int k = 0; k < 2 * HIDDEN; ++k) acc = fmaf(fused[k], hW1[k * HIDDEN + t], acc);
    h1s[t] = fmaxf(acc, 0.f);
    __syncthreads();
    if (t < N_CLASSES) {
        float o = hb2[t];
        for (int k = 0; k < HIDDEN; ++k) o = fmaf(h1s[k], hW2[k * N_CLASSES + t], o);
        out[(size_t)g * N_CLASSES + t] = o;
    }
}

// ---------------------------------------------------------------------------
extern "C" void kernel_launch(void* const* d_in, const int* in_sizes, int n_in,
                              void* d_out, int out_size, void* d_ws, size_t ws_size,
                              hipStream_t stream) {
    const float* x        = (const float*)d_in[0];
    const int*   eidx     = (const int*)d_in[1];
    const int*   batch    = (const int*)d_in[2];
    const float* gfeats   = (const float*)d_in[3];
    const float* c1_Wq = (const float*)d_in[4];  const float* c1_bq = (const float*)d_in[5];
    const float* c1_Wk = (const float*)d_in[6];  const float* c1_bk = (const float*)d_in[7];
    const float* c1_Wv = (const float*)d_in[8];  const float* c1_bv = (const float*)d_in[9];
    const float* c1_Ws = (const float*)d_in[10]; const float* c1_bs = (const float*)d_in[11];
    const float* c2_Wq = (const float*)d_in[12]; const float* c2_bq = (const float*)d_in[13];
    const float* c2_Wk = (const float*)d_in[14]; const float* c2_bk = (const float*)d_in[15];
    const float* c2_Wv = (const float*)d_in[16]; const float* c2_bv = (const float*)d_in[17];
    const float* c2_Ws = (const float*)d_in[18]; const float* c2_bs = (const float*)d_in[19];
    const float* g_W1 = (const float*)d_in[20]; const float* g_b1 = (const float*)d_in[21];
    const float* g_W2 = (const float*)d_in[22]; const float* g_b2 = (const float*)d_in[23];
    const float* h_W1 = (const float*)d_in[24]; const float* h_b1 = (const float*)d_in[25];
    const float* h_W2 = (const float*)d_in[26]; const float* h_b2 = (const float*)d_in[27];
    float* out = (float*)d_out;

    const int* srcp = eidx;
    const int* dstp = eidx + N_EDGES;

    // ---- workspace layout (all region sizes multiples of 16 B) ----
    char* base = (char*)d_ws;
    uchar_t*  kvb  = (uchar_t*)base;  base += (size_t)N_NODES * 512;         // 25.6 MB
    ushort_t* qb   = (ushort_t*)base; base += (size_t)N_NODES * 256 * 2;     // 25.6 MB
    float*    skipf = (float*)base;   base += (size_t)N_NODES * HIDDEN * 4;  // 12.8 MB
    ushort_t* h1b  = (ushort_t*)base; base += (size_t)N_NODES * HIDDEN * 2;  //  6.4 MB
    float*    h2   = (float*)base;    base += (size_t)N_NODES * HIDDEN * 4;  // 12.8 MB
    ushort_t* Wt   = (ushort_t*)base; base += (size_t)IN_CH * QKV_COLS * 2;  // 213 KB (max K)
    float*    bcat = (float*)base;    base += QKV_COLS * 4;
    float*    gsum = (float*)base;    base += N_GRAPHS * HIDDEN * 4;
    int* ib = (int*)base;
    size_t oi = 0;
    int* deg    = ib + oi; oi += N_NODES;
    int* incl   = ib + oi; oi += N_NODES;
    int* bsums  = ib + oi; oi += 64;
    int* boff   = ib + oi; oi += 64;
    int* rowptr = ib + oi; oi += N_NODES + 4;
    int* cur    = ib + oi; oi += N_NODES;
    int* colb   = ib + oi; oi += N_EDGES;
    int* gcnt   = ib + oi; oi += 64;

    const int NB1 = (N_NODES + 1023) / 1024;   // 49
    const int EB  = (N_EDGES + 255) / 256;     // 3125
    const int NBS = (N_NODES + 255) / 256;     // 196

    // ---- CSR build (shared by both conv layers) ----
    hipMemsetAsync(deg, 0, N_NODES * sizeof(int), stream);
    count_deg<<<EB, 256, 0, stream>>>(dstp, deg);
    scan1<<<NB1, 1024, 0, stream>>>(deg, incl, bsums, N_NODES);
    scan2<<<1, 64, 0, stream>>>(bsums, boff, NB1);
    scan3<<<NBS, 256, 0, stream>>>(deg, incl, boff, rowptr, cur, N_NODES);
    fill_col<<<EB, 256, 0, stream>>>(srcp, dstp, cur, colb);

    dim3 gemm_grid(QKV_COLS / 64, (N_NODES + 127) / 128);   // 13 x 391
    dim3 attn_block(64, 4);
    int attn_grid = (N_NODES + 3) / 4;                      // 12500

    // ---- conv1 (A = x fp32, cast during LDS staging) ----
    concat_w_t<<<(IN_CH * QKV_COLS + 255) / 256, 256, 0, stream>>>(
        c1_Wq, c1_Wk, c1_Wv, c1_Ws, c1_bq, c1_bk, c1_bv, c1_bs, Wt, bcat, IN_CH);
    gemm_v4<IN_CH, true><<<gemm_grid, 256, 0, stream>>>(x, Wt, bcat, qb, kvb, skipf, N_NODES);
    attn_agg3<true><<<attn_grid, attn_block, 0, stream>>>(qb, kvb, skipf, rowptr, colb, h1b);

    // ---- conv2 (A = h1b bf16; reuses qb/kvb/skipf buffers) ----
    concat_w_t<<<(HIDDEN * QKV_COLS + 255) / 256, 256, 0, stream>>>(
        c2_Wq, c2_Wk, c2_Wv, c2_Ws, c2_bq, c2_bk, c2_bv, c2_bs, Wt, bcat, HIDDEN);
    gemm_v4<HIDDEN, false><<<gemm_grid, 256, 0, stream>>>(h1b, Wt, bcat, qb, kvb, skipf, N_NODES);
    attn_agg3<false><<<attn_grid, attn_block, 0, stream>>>(qb, kvb, skipf, rowptr, colb, h2);

    // ---- pool + head ----
    pool_mean<<<N_GRAPHS, 256, 0, stream>>>(h2, batch, gsum, gcnt);
    mlp_head<<<N_GRAPHS, 64, 0, stream>>>(gsum, gcnt, gfeats,
                                          g_W1, g_b1, g_W2, g_b2,
                                          h_W1, h_b1, h_W2, h_b2, out);
}

// Round 6
// 499.087 us; speedup vs baseline: 2.0400x; 1.0187x over previous
//
#include <hip/hip_runtime.h>
#include <hip/hip_bf16.h>
#include <math.h>

#define N_NODES   50000
#define N_EDGES   800000
#define N_GRAPHS  64
#define IN_CH     128
#define GLOBAL_DIM 256
#define HIDDEN    64
#define HEADS     4
#define N_CLASSES 10
#define QKV_COLS  832   // 256 q | 256 k | 256 v | 64 skip

typedef unsigned short ushort_t;
typedef unsigned int uint_t;
typedef unsigned char uchar_t;
typedef __attribute__((ext_vector_type(8))) short short8;
typedef __attribute__((ext_vector_type(4))) float floatx4;
typedef __attribute__((ext_vector_type(2))) float floatx2;

// ---------------------------------------------------------------------------
// helpers
// ---------------------------------------------------------------------------
__device__ __forceinline__ ushort_t bf16rne(float f) {
    uint_t b = __float_as_uint(f);
    b += 0x7fffu + ((b >> 16) & 1u);
    return (ushort_t)(b >> 16);
}
__device__ __forceinline__ float4 bf4_unpack(uint_t lo, uint_t hi) {
    float4 f;
    f.x = __uint_as_float(lo << 16);
    f.y = __uint_as_float(lo & 0xffff0000u);
    f.z = __uint_as_float(hi << 16);
    f.w = __uint_as_float(hi & 0xffff0000u);
    return f;
}
__device__ __forceinline__ uchar_t fp8e4m3(float f) {
    int v = __builtin_amdgcn_cvt_pk_fp8_f32(f, 0.f, 0, false);
    return (uchar_t)(v & 0xff);
}

// ---------------------------------------------------------------------------
// CSR build: deg -> inclusive scan -> rowptr/cursor -> fill col (src ids)
// ---------------------------------------------------------------------------
__global__ void count_deg(const int* __restrict__ dst, int* __restrict__ deg) {
    int e = blockIdx.x * 256 + threadIdx.x;
    if (e < N_EDGES) atomicAdd(&deg[dst[e]], 1);
}

__global__ void scan1(const int* __restrict__ deg, int* __restrict__ incl,
                      int* __restrict__ bsums, int n) {
    __shared__ int sh[1024];
    int t = threadIdx.x;
    int gid = blockIdx.x * 1024 + t;
    int v = (gid < n) ? deg[gid] : 0;
    sh[t] = v;
    __syncthreads();
    for (int off = 1; off < 1024; off <<= 1) {
        int tmp = (t >= off) ? sh[t - off] : 0;
        __syncthreads();
        sh[t] += tmp;
        __syncthreads();
    }
    if (gid < n) incl[gid] = sh[t];
    if (t == 1023) bsums[blockIdx.x] = sh[1023];
}

__global__ void scan2(const int* __restrict__ bsums, int* __restrict__ boff, int nb) {
    int t = threadIdx.x;   // 64 threads, nb <= 64
    int v = (t < nb) ? bsums[t] : 0;
    int incl = v;
#pragma unroll
    for (int off = 1; off < 64; off <<= 1) {
        int u = __shfl_up(incl, off);
        if (t >= off) incl += u;
    }
    if (t < nb) boff[t] = incl - v;   // exclusive
}

__global__ void scan3(const int* __restrict__ deg, const int* __restrict__ incl,
                      const int* __restrict__ boff, int* __restrict__ rowptr,
                      int* __restrict__ cur, int n) {
    int gid = blockIdx.x * 256 + threadIdx.x;
    if (gid < n) {
        int b = gid >> 10;
        int in = incl[gid] + boff[b];
        int ex = in - deg[gid];
        rowptr[gid] = ex;
        cur[gid] = ex;
        if (gid == n - 1) rowptr[n] = in;
    }
}

__global__ void fill_col(const int* __restrict__ src, const int* __restrict__ dst,
                         int* __restrict__ cur, int* __restrict__ col) {
    int e = blockIdx.x * 256 + threadIdx.x;
    if (e < N_EDGES) {
        int d = dst[e];
        int pos = atomicAdd(&cur[d], 1);
        col[pos] = src[e];
    }
}

// ---------------------------------------------------------------------------
// Concat+transpose BOTH layers' weights in one launch.
// Wt1[c][k] K=128, Wt2[c][k] K=64 (bf16); bcat1/2 fp32.
// ---------------------------------------------------------------------------
__global__ void concat_all(const float* __restrict__ W1q, const float* __restrict__ W1k,
                           const float* __restrict__ W1v, const float* __restrict__ W1s,
                           const float* __restrict__ b1q, const float* __restrict__ b1k,
                           const float* __restrict__ b1v, const float* __restrict__ b1s,
                           const float* __restrict__ W2q, const float* __restrict__ W2k,
                           const float* __restrict__ W2v, const float* __restrict__ W2s,
                           const float* __restrict__ b2q, const float* __restrict__ b2k,
                           const float* __restrict__ b2v, const float* __restrict__ b2s,
                           ushort_t* __restrict__ Wt1, ushort_t* __restrict__ Wt2,
                           float* __restrict__ bcat1, float* __restrict__ bcat2) {
    int idx = blockIdx.x * 256 + threadIdx.x;
    const int T1 = IN_CH * QKV_COLS;          // 106496
    const int T2 = HIDDEN * QKV_COLS;         // 53248
    if (idx < T1) {
        int c = idx / IN_CH, k = idx % IN_CH;
        float v;
        if (c < 256)      v = W1q[k * 256 + c];
        else if (c < 512) v = W1k[k * 256 + (c - 256)];
        else if (c < 768) v = W1v[k * 256 + (c - 512)];
        else              v = W1s[k * 64  + (c - 768)];
        Wt1[idx] = bf16rne(v);
    } else if (idx < T1 + T2) {
        int i2 = idx - T1;
        int c = i2 / HIDDEN, k = i2 % HIDDEN;
        float v;
        if (c < 256)      v = W2q[k * 256 + c];
        else if (c < 512) v = W2k[k * 256 + (c - 256)];
        else if (c < 768) v = W2v[k * 256 + (c - 512)];
        else              v = W2s[k * 64  + (c - 768)];
        Wt2[i2] = bf16rne(v);
    }
    if (idx < QKV_COLS) {
        float b, b2;
        if (idx < 256)      { b = b1q[idx];       b2 = b2q[idx]; }
        else if (idx < 512) { b = b1k[idx - 256]; b2 = b2k[idx - 256]; }
        else if (idx < 768) { b = b1v[idx - 512]; b2 = b2v[idx - 512]; }
        else                { b = b1s[idx - 768]; b2 = b2s[idx - 768]; }
        bcat1[idx] = b;
        bcat2[idx] = b2;
    }
}

// ---------------------------------------------------------------------------
// bf16 MFMA GEMM v5: XCD-aware swizzled 1D grid.
// idx -> xcd = idx&7, j = idx>>3, ct = j%13, strip = (j/13)*8 + xcd.
// All 13 col-tiles of one 128-row strip share idx%8 -> same XCD -> A strip
// fetched once per XCD-local L2.
// Outputs: ct 0-3  -> qb8  fp8 [N,256]         (byte c)
//          ct 4-7  -> kvb  fp8 k: byte 16*(c>>3)+(c&7)
//          ct 8-11 -> kvb  fp8 v: byte 16*(c>>3)+8+(c&7)
//          ct 12   -> skipb bf16 [N,64]
// Epilogue stages tile in LDS (reuse As) with non-pow2 strides, wide stores.
// ---------------------------------------------------------------------------
template <int K, bool A_FP32>
__global__ __launch_bounds__(256) void gemm_v5(const void* __restrict__ Av,
                                               const ushort_t* __restrict__ Wt,
                                               const float* __restrict__ bias,
                                               uchar_t* __restrict__ qb8,
                                               uchar_t* __restrict__ kvb,
                                               ushort_t* __restrict__ skipb,
                                               int N, int RB) {
    constexpr int KP = K + 8;      // padded LDS row stride (bf16 units)
    constexpr int C8 = K / 8;      // 16B bf16 chunks per row
    __shared__ ushort_t As[128 * KP] __attribute__((aligned(16)));
    __shared__ ushort_t Bs[64 * KP] __attribute__((aligned(16)));

    const int t = threadIdx.x;
    const int idx0 = blockIdx.x;
    const int xcd = idx0 & 7;
    const int j = idx0 >> 3;
    const int ct = j % 13;
    const int strip = (j / 13) * 8 + xcd;
    if (strip >= RB) return;
    const int base_r = strip * 128;
    const int base_c = ct * 64;

    // ---- stage A tile (128 x K) ----
    if (A_FP32) {
        const float* A = (const float*)Av;
        constexpr int C4 = K / 4;
#pragma unroll
        for (int i = 0; i < (128 * C4) / 256; ++i) {
            int ii = t + i * 256;
            int r = ii / C4, c = ii % C4;
            int gr = base_r + r;
            float4 av = make_float4(0.f, 0.f, 0.f, 0.f);
            if (gr < N) av = *(const float4*)(A + (size_t)gr * K + c * 4);
            uint2 u;
            u.x = (uint_t)bf16rne(av.x) | ((uint_t)bf16rne(av.y) << 16);
            u.y = (uint_t)bf16rne(av.z) | ((uint_t)bf16rne(av.w) << 16);
            *(uint2*)(As + r * KP + c * 4) = u;
        }
    } else {
        const ushort_t* A = (const ushort_t*)Av;
#pragma unroll
        for (int i = 0; i < (128 * C8) / 256; ++i) {
            int ii = t + i * 256;
            int r = ii / C8, c = ii % C8;
            int gr = base_r + r;
            uint4 val = make_uint4(0u, 0u, 0u, 0u);
            if (gr < N) val = *(const uint4*)(A + (size_t)gr * K + c * 8);
            *(uint4*)(As + r * KP + c * 8) = val;
        }
    }
    // ---- stage B tile (64 cols of Wt) ----
#pragma unroll
    for (int i = 0; i < (64 * C8) / 256; ++i) {
        int ii = t + i * 256;
        int n = ii / C8, c = ii % C8;
        *(uint4*)(Bs + n * KP + c * 8) =
            *(const uint4*)(Wt + (size_t)(base_c + n) * K + c * 8);
    }
    __syncthreads();

    const int wave = t >> 6, lane = t & 63;
    const int quad = lane >> 4, m16 = lane & 15;

    floatx4 acc[2][4];
#pragma unroll
    for (int rt = 0; rt < 2; ++rt)
#pragma unroll
        for (int c2 = 0; c2 < 4; ++c2) acc[rt][c2] = (floatx4){0.f, 0.f, 0.f, 0.f};
#pragma unroll
    for (int kc = 0; kc < K / 32; ++kc) {
        int ko = kc * 32 + quad * 8;
        short8 a0 = *(const short8*)(As + (wave * 32 + m16) * KP + ko);
        short8 a1 = *(const short8*)(As + (wave * 32 + 16 + m16) * KP + ko);
#pragma unroll
        for (int c2 = 0; c2 < 4; ++c2) {
            short8 b = *(const short8*)(Bs + (c2 * 16 + m16) * KP + ko);
            acc[0][c2] = __builtin_amdgcn_mfma_f32_16x16x32_bf16(a0, b, acc[0][c2], 0, 0, 0);
            acc[1][c2] = __builtin_amdgcn_mfma_f32_16x16x32_bf16(a1, b, acc[1][c2], 0, 0, 0);
        }
    }

    // add bias in-register
    float bb[4];
#pragma unroll
    for (int c2 = 0; c2 < 4; ++c2) bb[c2] = bias[base_c + c2 * 16 + m16];
#pragma unroll
    for (int rt = 0; rt < 2; ++rt)
#pragma unroll
        for (int c2 = 0; c2 < 4; ++c2)
#pragma unroll
            for (int r = 0; r < 4; ++r) acc[rt][c2][r] += bb[c2];

    __syncthreads();   // all waves done reading As/Bs; reuse As for epilogue

    // lane's element (rt,c2,r): row_l = wave*32+rt*16+quad*4+r, col_l = c2*16+m16
    if (ct < 12) {
        // ---- fp8 tile [128][64] bytes, LDS stride 80 (non-pow2, 8-aligned) ----
        uchar_t* ep = (uchar_t*)As;
#pragma unroll
        for (int c2 = 0; c2 < 4; ++c2) {
            int col_l = c2 * 16 + m16;
#pragma unroll
            for (int rt = 0; rt < 2; ++rt)
#pragma unroll
                for (int r = 0; r < 4; ++r)
                    ep[(wave * 32 + rt * 16 + quad * 4 + r) * 80 + col_l] =
                        fp8e4m3(acc[rt][c2][r]);
        }
        __syncthreads();
        const bool isq = (ct < 4);
        const bool isv = (ct >= 8);
        const int j0 = (base_c - (isv ? 512 : 256)) >> 3;
        const int sub = isv ? 8 : 0;
#pragma unroll
        for (int i = 0; i < 4; ++i) {
            int ii = t + i * 256;
            int row = ii >> 3, jj = ii & 7;
            int gr = base_r + row;
            if (gr < N) {
                uint2 val = *(const uint2*)(ep + row * 80 + jj * 8);
                if (isq)
                    *(uint2*)(qb8 + (size_t)gr * 256 + base_c + jj * 8) = val;
                else
                    *(uint2*)(kvb + (size_t)gr * 512 + 16 * (j0 + jj) + sub) = val;
            }
        }
    } else {
        // ---- skip tile: bf16 [128][64], LDS stride 72 ushorts (144B) ----
        ushort_t* ep = As;
#pragma unroll
        for (int c2 = 0; c2 < 4; ++c2) {
            int col_l = c2 * 16 + m16;
#pragma unroll
            for (int rt = 0; rt < 2; ++rt)
#pragma unroll
                for (int r = 0; r < 4; ++r)
                    ep[(wave * 32 + rt * 16 + quad * 4 + r) * 72 + col_l] =
                        bf16rne(acc[rt][c2][r]);
        }
        __syncthreads();
#pragma unroll
        for (int i = 0; i < 4; ++i) {
            int ii = t + i * 256;
            int row = ii >> 3, ch = ii & 7;
            int gr = base_r + row;
            if (gr < N)
                *(uint4*)(skipb + (size_t)gr * 64 + ch * 8) =
                    *(const uint4*)(ep + row * 72 + ch * 8);
        }
    }
}

// ---------------------------------------------------------------------------
// TransformerConv aggregation v4: one wave per dst node, half-wave per edge,
// q fp8, k/v fp8 interleaved 8-dim chunks, skip bf16.
// sl = lane&31 owns dims [8*sl, 8*sl+8); head = sl>>3; dot-reduce shfl 1,2,4.
// ---------------------------------------------------------------------------
__device__ __forceinline__ void edge_step(uint4 kv, const float* qf,
                                          float& z, float* ac) {
    floatx2 k01 = __builtin_amdgcn_cvt_pk_f32_fp8(kv.x, false);
    floatx2 k23 = __builtin_amdgcn_cvt_pk_f32_fp8(kv.x, true);
    floatx2 k45 = __builtin_amdgcn_cvt_pk_f32_fp8(kv.y, false);
    floatx2 k67 = __builtin_amdgcn_cvt_pk_f32_fp8(kv.y, true);
    float d = qf[0] * k01[0] + qf[1] * k01[1] + qf[2] * k23[0] + qf[3] * k23[1]
            + qf[4] * k45[0] + qf[5] * k45[1] + qf[6] * k67[0] + qf[7] * k67[1];
    d += __shfl_xor(d, 1);
    d += __shfl_xor(d, 2);
    d += __shfl_xor(d, 4);
    float p = __expf(d * 0.125f);
    z += p;
    floatx2 v01 = __builtin_amdgcn_cvt_pk_f32_fp8(kv.z, false);
    floatx2 v23 = __builtin_amdgcn_cvt_pk_f32_fp8(kv.z, true);
    floatx2 v45 = __builtin_amdgcn_cvt_pk_f32_fp8(kv.w, false);
    floatx2 v67 = __builtin_amdgcn_cvt_pk_f32_fp8(kv.w, true);
    ac[0] = fmaf(p, v01[0], ac[0]); ac[1] = fmaf(p, v01[1], ac[1]);
    ac[2] = fmaf(p, v23[0], ac[2]); ac[3] = fmaf(p, v23[1], ac[3]);
    ac[4] = fmaf(p, v45[0], ac[4]); ac[5] = fmaf(p, v45[1], ac[5]);
    ac[6] = fmaf(p, v67[0], ac[6]); ac[7] = fmaf(p, v67[1], ac[7]);
}

template <bool OUT_BF16>
__global__ __launch_bounds__(256) void attn_agg4(const uchar_t* __restrict__ qb8,
                                                 const uchar_t* __restrict__ kvb,
                                                 const ushort_t* __restrict__ skipb,
                                                 const int* __restrict__ rowptr,
                                                 const int* __restrict__ col,
                                                 void* __restrict__ hout) {
    int node = blockIdx.x * 4 + threadIdx.y;
    if (node >= N_NODES) return;
    int lane = threadIdx.x;
    int half = lane >> 5, sl = lane & 31;
    uint2 qd = *(const uint2*)(qb8 + (size_t)node * 256 + sl * 8);
    floatx2 q01 = __builtin_amdgcn_cvt_pk_f32_fp8(qd.x, false);
    floatx2 q23 = __builtin_amdgcn_cvt_pk_f32_fp8(qd.x, true);
    floatx2 q45 = __builtin_amdgcn_cvt_pk_f32_fp8(qd.y, false);
    floatx2 q67 = __builtin_amdgcn_cvt_pk_f32_fp8(qd.y, true);
    float qf[8] = {q01[0], q01[1], q23[0], q23[1], q45[0], q45[1], q67[0], q67[1]};
    float ac[8] = {0.f, 0.f, 0.f, 0.f, 0.f, 0.f, 0.f, 0.f};
    float z = 0.f;
    int beg = rowptr[node], end = rowptr[node + 1];
    int e = beg + half;
    const size_t loff = (size_t)sl * 16;
    for (; e + 6 < end; e += 8) {
        int s0 = col[e], s1 = col[e + 2], s2 = col[e + 4], s3 = col[e + 6];
        uint4 kv0 = *(const uint4*)(kvb + (size_t)s0 * 512 + loff);
        uint4 kv1 = *(const uint4*)(kvb + (size_t)s1 * 512 + loff);
        uint4 kv2 = *(const uint4*)(kvb + (size_t)s2 * 512 + loff);
        uint4 kv3 = *(const uint4*)(kvb + (size_t)s3 * 512 + loff);
        edge_step(kv0, qf, z, ac);
        edge_step(kv1, qf, z, ac);
        edge_step(kv2, qf, z, ac);
        edge_step(kv3, qf, z, ac);
    }
    for (; e < end; e += 2) {
        uint4 kv0 = *(const uint4*)(kvb + (size_t)col[e] * 512 + loff);
        edge_step(kv0, qf, z, ac);
    }
    z += __shfl_xor(z, 32);
#pragma unroll
    for (int i = 0; i < 8; ++i) ac[i] += __shfl_xor(ac[i], 32);
    float inv = (z > 0.f) ? (1.f / z) : 0.f;
#pragma unroll
    for (int i = 0; i < 8; ++i) ac[i] *= inv;
#pragma unroll
    for (int i = 0; i < 8; ++i) {
        ac[i] += __shfl_xor(ac[i], 8);
        ac[i] += __shfl_xor(ac[i], 16);
    }
    if (lane < 8) {   // lane holds output dims [8*lane, 8*lane+8)
        uint4 su = *(const uint4*)(skipb + (size_t)node * 64 + lane * 8);
        float4 s0 = bf4_unpack(su.x, su.y);
        float4 s1 = bf4_unpack(su.z, su.w);
        float o0 = fmaxf(ac[0] * 0.25f + s0.x, 0.f);
        float o1 = fmaxf(ac[1] * 0.25f + s0.y, 0.f);
        float o2 = fmaxf(ac[2] * 0.25f + s0.z, 0.f);
        float o3 = fmaxf(ac[3] * 0.25f + s0.w, 0.f);
        float o4 = fmaxf(ac[4] * 0.25f + s1.x, 0.f);
        float o5 = fmaxf(ac[5] * 0.25f + s1.y, 0.f);
        float o6 = fmaxf(ac[6] * 0.25f + s1.z, 0.f);
        float o7 = fmaxf(ac[7] * 0.25f + s1.w, 0.f);
        if (OUT_BF16) {
            uint4 u;
            u.x = (uint_t)bf16rne(o0) | ((uint_t)bf16rne(o1) << 16);
            u.y = (uint_t)bf16rne(o2) | ((uint_t)bf16rne(o3) << 16);
            u.z = (uint_t)bf16rne(o4) | ((uint_t)bf16rne(o5) << 16);
            u.w = (uint_t)bf16rne(o6) | ((uint_t)bf16rne(o7) << 16);
            *(uint4*)((ushort_t*)hout + (size_t)node * HIDDEN + lane * 8) = u;
        } else {
            float* op = (float*)hout + (size_t)node * HIDDEN + lane * 8;
            *(float4*)(op)     = make_float4(o0, o1, o2, o3);
            *(float4*)(op + 4) = make_float4(o4, o5, o6, o7);
        }
    }
}

// ---------------------------------------------------------------------------
// Per-graph mean pool (batch is sorted -> binary search boundaries, no atomics)
// ---------------------------------------------------------------------------
__global__ void pool_mean(const float* __restrict__ h, const int* __restrict__ batch,
                          float* __restrict__ gsum, int* __restrict__ gcnt) {
    int g = blockIdx.x;
    int lo = 0, hi = N_NODES;
    while (lo < hi) { int mid = (lo + hi) >> 1; if (batch[mid] < g) lo = mid + 1; else hi = mid; }
    int start = lo;
    hi = N_NODES;
    while (lo < hi) { int mid = (lo + hi) >> 1; if (batch[mid] < g + 1) lo = mid + 1; else hi = mid; }
    int end = lo;
    int t = threadIdx.x;
    int d = t & 63, chunk = t >> 6;   // 256 threads: 4 chunks x 64 dims
    float acc = 0.f;
    for (int n = start + chunk; n < end; n += 4) acc += h[(size_t)n * HIDDEN + d];
    __shared__ float sh[256];
    sh[t] = acc;
    __syncthreads();
    if (chunk == 0) {
        gsum[g * HIDDEN + d] = sh[d] + sh[64 + d] + sh[128 + d] + sh[192 + d];
        if (d == 0) gcnt[g] = end - start;
    }
}

// ---------------------------------------------------------------------------
// Final MLP head: one block (64 threads) per graph
// ---------------------------------------------------------------------------
__global__ __launch_bounds__(64) void mlp_head(const float* __restrict__ gsum,
                                               const int* __restrict__ gcnt,
                                               const float* __restrict__ gf,
                                               const float* __restrict__ gW1, const float* __restrict__ gb1,
                                               const float* __restrict__ gW2, const float* __restrict__ gb2,
                                               const float* __restrict__ hW1, const float* __restrict__ hb1,
                                               const float* __restrict__ hW2, const float* __restrict__ hb2,
                                               float* __restrict__ out) {
    int g = blockIdx.x;
    int t = threadIdx.x;   // 64 threads
    __shared__ float gfs[GLOBAL_DIM];
    __shared__ float g1[HIDDEN];
    __shared__ float fused[2 * HIDDEN];
    __shared__ float h1s[HIDDEN];
    for (int i = t; i < GLOBAL_DIM; i += 64) gfs[i] = gf[(size_t)g * GLOBAL_DIM + i];
    float cnt = (float)gcnt[g];
    cnt = fmaxf(cnt, 1.0f);
    fused[t] = gsum[g * HIDDEN + t] / cnt;   // patch_emb
    __syncthreads();
    float acc = gb1[t];
    for (int k = 0; k < GLOBAL_DIM; ++k) acc = fmaf(gfs[k], gW1[k * HIDDEN + t], acc);
    g1[t] = fmaxf(acc, 0.f);
    __syncthreads();
    acc = gb2[t];
    for (int k = 0; k < HIDDEN; ++k) acc = fmaf(g1[k], gW2[k * HIDDEN + t], acc);
    fused[HIDDEN + t] = fmaxf(acc, 0.f);
    __syncthreads();
    acc = hb1[t];
    for (int k = 0; k < 2 * HIDDEN; ++k) acc = fmaf(fused[k], hW1[k * HIDDEN + t], acc);
    h1s[t] = fmaxf(acc, 0.f);
    __syncthreads();
    if (t < N_CLASSES) {
        float o = hb2[t];
        for (int k = 0; k < HIDDEN; ++k) o = fmaf(h1s[k], hW2[k * N_CLASSES + t], o);
        out[(size_t)g * N_CLASSES + t] = o;
    }
}

// ---------------------------------------------------------------------------
extern "C" void kernel_launch(void* const* d_in, const int* in_sizes, int n_in,
                              void* d_out, int out_size, void* d_ws, size_t ws_size,
                              hipStream_t stream) {
    const float* x        = (const float*)d_in[0];
    const int*   eidx     = (const int*)d_in[1];
    const int*   batch    = (const int*)d_in[2];
    const float* gfeats   = (const float*)d_in[3];
    const float* c1_Wq = (const float*)d_in[4];  const float* c1_bq = (const float*)d_in[5];
    const float* c1_Wk = (const float*)d_in[6];  const float* c1_bk = (const float*)d_in[7];
    const float* c1_Wv = (const float*)d_in[8];  const float* c1_bv = (const float*)d_in[9];
    const float* c1_Ws = (const float*)d_in[10]; const float* c1_bs = (const float*)d_in[11];
    const float* c2_Wq = (const float*)d_in[12]; const float* c2_bq = (const float*)d_in[13];
    const float* c2_Wk = (const float*)d_in[14]; const float* c2_bk = (const float*)d_in[15];
    const float* c2_Wv = (const float*)d_in[16]; const float* c2_bv = (const float*)d_in[17];
    const float* c2_Ws = (const float*)d_in[18]; const float* c2_bs = (const float*)d_in[19];
    const float* g_W1 = (const float*)d_in[20]; const float* g_b1 = (const float*)d_in[21];
    const float* g_W2 = (const float*)d_in[22]; const float* g_b2 = (const float*)d_in[23];
    const float* h_W1 = (const float*)d_in[24]; const float* h_b1 = (const float*)d_in[25];
    const float* h_W2 = (const float*)d_in[26]; const float* h_b2 = (const float*)d_in[27];
    float* out = (float*)d_out;

    const int* srcp = eidx;
    const int* dstp = eidx + N_EDGES;

    // ---- workspace layout (all region sizes multiples of 16 B) ----
    char* base = (char*)d_ws;
    uchar_t*  kvb  = (uchar_t*)base;  base += (size_t)N_NODES * 512;         // 25.6 MB
    uchar_t*  qb8  = (uchar_t*)base;  base += (size_t)N_NODES * 256;         // 12.8 MB
    ushort_t* skipb = (ushort_t*)base; base += (size_t)N_NODES * HIDDEN * 2; //  6.4 MB
    ushort_t* h1b  = (ushort_t*)base; base += (size_t)N_NODES * HIDDEN * 2;  //  6.4 MB
    float*    h2   = (float*)base;    base += (size_t)N_NODES * HIDDEN * 4;  // 12.8 MB
    ushort_t* Wt1  = (ushort_t*)base; base += (size_t)IN_CH * QKV_COLS * 2;  // 213 KB
    ushort_t* Wt2  = (ushort_t*)base; base += (size_t)HIDDEN * QKV_COLS * 2; // 107 KB
    float*    bcat1 = (float*)base;   base += QKV_COLS * 4;
    float*    bcat2 = (float*)base;   base += QKV_COLS * 4;
    float*    gsum = (float*)base;    base += N_GRAPHS * HIDDEN * 4;
    int* ib = (int*)base;
    size_t oi = 0;
    int* deg    = ib + oi; oi += N_NODES;
    int* incl   = ib + oi; oi += N_NODES;
    int* bsums  = ib + oi; oi += 64;
    int* boff   = ib + oi; oi += 64;
    int* rowptr = ib + oi; oi += N_NODES + 4;
    int* cur    = ib + oi; oi += N_NODES;
    int* colb   = ib + oi; oi += N_EDGES;
    int* gcnt   = ib + oi; oi += 64;

    const int NB1 = (N_NODES + 1023) / 1024;   // 49
    const int EB  = (N_EDGES + 255) / 256;     // 3125
    const int NBS = (N_NODES + 255) / 256;     // 196

    // ---- CSR build (shared by both conv layers) ----
    hipMemsetAsync(deg, 0, N_NODES * sizeof(int), stream);
    count_deg<<<EB, 256, 0, stream>>>(dstp, deg);
    scan1<<<NB1, 1024, 0, stream>>>(deg, incl, bsums, N_NODES);
    scan2<<<1, 64, 0, stream>>>(bsums, boff, NB1);
    scan3<<<NBS, 256, 0, stream>>>(deg, incl, boff, rowptr, cur, N_NODES);
    fill_col<<<EB, 256, 0, stream>>>(srcp, dstp, cur, colb);

    // ---- weights for both layers, one launch ----
    const int CT = IN_CH * QKV_COLS + HIDDEN * QKV_COLS;   // 159744
    concat_all<<<(CT + 255) / 256, 256, 0, stream>>>(
        c1_Wq, c1_Wk, c1_Wv, c1_Ws, c1_bq, c1_bk, c1_bv, c1_bs,
        c2_Wq, c2_Wk, c2_Wv, c2_Ws, c2_bq, c2_bk, c2_bv, c2_bs,
        Wt1, Wt2, bcat1, bcat2);

    const int RB = (N_NODES + 127) / 128;                  // 391
    const int GG = 8 * 13 * ((RB + 7) / 8);                // 5096
    dim3 attn_block(64, 4);
    int attn_grid = (N_NODES + 3) / 4;                     // 12500

    // ---- conv1 (A = x fp32, cast during LDS staging) ----
    gemm_v5<IN_CH, true><<<GG, 256, 0, stream>>>(x, Wt1, bcat1, qb8, kvb, skipb, N_NODES, RB);
    attn_agg4<true><<<attn_grid, attn_block, 0, stream>>>(qb8, kvb, skipb, rowptr, colb, h1b);

    // ---- conv2 (A = h1b bf16; reuses qb8/kvb/skipb buffers) ----
    gemm_v5<HIDDEN, false><<<GG, 256, 0, stream>>>(h1b, Wt2, bcat2, qb8, kvb, skipb, N_NODES, RB);
    attn_agg4<false><<<attn_grid, attn_block, 0, stream>>>(qb8, kvb, skipb, rowptr, colb, h2);

    // ---- pool + head ----
    pool_mean<<<N_GRAPHS, 256, 0, stream>>>(h2, batch, gsum, gcnt);
    mlp_head<<<N_GRAPHS, 64, 0, stream>>>(gsum, gcnt, gfeats,
                                          g_W1, g_b1, g_W2, g_b2,
                                          h_W1, h_b1, h_W2, h_b2, out);
}

// Round 7
// 453.825 us; speedup vs baseline: 2.2435x; 1.0997x over previous
//
#include <hip/hip_runtime.h>
#include <hip/hip_bf16.h>
#include <math.h>

#define N_NODES   50000
#define N_EDGES   800000
#define N_GRAPHS  64
#define IN_CH     128
#define GLOBAL_DIM 256
#define HIDDEN    64
#define HEADS     4
#define N_CLASSES 10
#define QKV_COLS  832   // 256 q | 256 k | 256 v | 64 skip

typedef unsigned short ushort_t;
typedef unsigned int uint_t;
typedef unsigned char uchar_t;
typedef __attribute__((ext_vector_type(8))) short short8;
typedef __attribute__((ext_vector_type(4))) float floatx4;
typedef __attribute__((ext_vector_type(2))) float floatx2;

// ---------------------------------------------------------------------------
// helpers
// ---------------------------------------------------------------------------
__device__ __forceinline__ ushort_t bf16rne(float f) {
    uint_t b = __float_as_uint(f);
    b += 0x7fffu + ((b >> 16) & 1u);
    return (ushort_t)(b >> 16);
}
__device__ __forceinline__ float4 bf4_unpack(uint_t lo, uint_t hi) {
    float4 f;
    f.x = __uint_as_float(lo << 16);
    f.y = __uint_as_float(lo & 0xffff0000u);
    f.z = __uint_as_float(hi << 16);
    f.w = __uint_as_float(hi & 0xffff0000u);
    return f;
}
__device__ __forceinline__ uchar_t fp8e4m3(float f) {
    int v = __builtin_amdgcn_cvt_pk_fp8_f32(f, 0.f, 0, false);
    return (uchar_t)(v & 0xff);
}

// ---------------------------------------------------------------------------
// CSR build
// ---------------------------------------------------------------------------
__global__ void count_deg(const int* __restrict__ dst, int* __restrict__ deg) {
    int idx = blockIdx.x * 256 + threadIdx.x;
    for (int e = idx; e < N_EDGES; e += 782 * 256)
        atomicAdd(&deg[dst[e]], 1);
}

__global__ void scan1(const int* __restrict__ deg, int* __restrict__ incl,
                      int* __restrict__ bsums, int n) {
    __shared__ int sh[1024];
    int t = threadIdx.x;
    int gid = blockIdx.x * 1024 + t;
    int v = (gid < n) ? deg[gid] : 0;
    sh[t] = v;
    __syncthreads();
    for (int off = 1; off < 1024; off <<= 1) {
        int tmp = (t >= off) ? sh[t - off] : 0;
        __syncthreads();
        sh[t] += tmp;
        __syncthreads();
    }
    if (gid < n) incl[gid] = sh[t];
    if (t == 1023) bsums[blockIdx.x] = sh[1023];
}

// scan3 with scan2 fused: each 256-wide block spans exactly one scan1 block
// (b = blockIdx.x>>2), so boff[b] = sum(bsums[0..b)) via one wave reduce.
__global__ void scan3f(const int* __restrict__ deg, const int* __restrict__ incl,
                       const int* __restrict__ bsums, int* __restrict__ rowptr,
                       int* __restrict__ cur, int n) {
    __shared__ int sb;
    int t = threadIdx.x;
    int b = (int)(blockIdx.x >> 2);        // scan1 block id (1024/256)
    if (t < 64) {
        int v = (t < b) ? bsums[t] : 0;    // b <= 48 < 64
#pragma unroll
        for (int off = 1; off < 64; off <<= 1) v += __shfl_xor(v, off);
        if (t == 0) sb = v;
    }
    __syncthreads();
    int gid = blockIdx.x * 256 + t;
    if (gid < n) {
        int in = incl[gid] + sb;
        int ex = in - deg[gid];
        rowptr[gid] = ex;
        cur[gid] = ex;
        if (gid == n - 1) rowptr[n] = in;
    }
}

__global__ void fill_col(const int* __restrict__ src, const int* __restrict__ dst,
                         int* __restrict__ cur, int* __restrict__ col) {
    int e = blockIdx.x * 256 + threadIdx.x;
    if (e < N_EDGES) {
        int d = dst[e];
        int pos = atomicAdd(&cur[d], 1);
        col[pos] = src[e];
    }
}

// ---------------------------------------------------------------------------
// cast fp32 -> bf16, 8 elems/thread (x -> xb for conv1 A operand)
// ---------------------------------------------------------------------------
__global__ void cast_bf16_x8(const float* __restrict__ in, ushort_t* __restrict__ out, int n8) {
    int idx = blockIdx.x * 256 + threadIdx.x;
    if (idx >= n8) return;
    size_t i = (size_t)idx * 8;
    float4 a = *(const float4*)(in + i);
    float4 b = *(const float4*)(in + i + 4);
    uint4 u;
    u.x = (uint_t)bf16rne(a.x) | ((uint_t)bf16rne(a.y) << 16);
    u.y = (uint_t)bf16rne(a.z) | ((uint_t)bf16rne(a.w) << 16);
    u.z = (uint_t)bf16rne(b.x) | ((uint_t)bf16rne(b.y) << 16);
    u.w = (uint_t)bf16rne(b.z) | ((uint_t)bf16rne(b.w) << 16);
    *(uint4*)(out + i) = u;
}

// ---------------------------------------------------------------------------
// Concat+transpose BOTH layers' weights in one launch.
// ---------------------------------------------------------------------------
__global__ void concat_all(const float* __restrict__ W1q, const float* __restrict__ W1k,
                           const float* __restrict__ W1v, const float* __restrict__ W1s,
                           const float* __restrict__ b1q, const float* __restrict__ b1k,
                           const float* __restrict__ b1v, const float* __restrict__ b1s,
                           const float* __restrict__ W2q, const float* __restrict__ W2k,
                           const float* __restrict__ W2v, const float* __restrict__ W2s,
                           const float* __restrict__ b2q, const float* __restrict__ b2k,
                           const float* __restrict__ b2v, const float* __restrict__ b2s,
                           ushort_t* __restrict__ Wt1, ushort_t* __restrict__ Wt2,
                           float* __restrict__ bcat1, float* __restrict__ bcat2) {
    int idx = blockIdx.x * 256 + threadIdx.x;
    const int T1 = IN_CH * QKV_COLS;
    const int T2 = HIDDEN * QKV_COLS;
    if (idx < T1) {
        int c = idx / IN_CH, k = idx % IN_CH;
        float v;
        if (c < 256)      v = W1q[k * 256 + c];
        else if (c < 512) v = W1k[k * 256 + (c - 256)];
        else if (c < 768) v = W1v[k * 256 + (c - 512)];
        else              v = W1s[k * 64  + (c - 768)];
        Wt1[idx] = bf16rne(v);
    } else if (idx < T1 + T2) {
        int i2 = idx - T1;
        int c = i2 / HIDDEN, k = i2 % HIDDEN;
        float v;
        if (c < 256)      v = W2q[k * 256 + c];
        else if (c < 512) v = W2k[k * 256 + (c - 256)];
        else if (c < 768) v = W2v[k * 256 + (c - 512)];
        else              v = W2s[k * 64  + (c - 768)];
        Wt2[i2] = bf16rne(v);
    }
    if (idx < QKV_COLS) {
        float b, b2;
        if (idx < 256)      { b = b1q[idx];       b2 = b2q[idx]; }
        else if (idx < 512) { b = b1k[idx - 256]; b2 = b2k[idx - 256]; }
        else if (idx < 768) { b = b1v[idx - 512]; b2 = b2v[idx - 512]; }
        else                { b = b1s[idx - 768]; b2 = b2s[idx - 768]; }
        bcat1[idx] = b;
        bcat2[idx] = b2;
    }
}

// ---------------------------------------------------------------------------
// bf16 MFMA GEMM v6: NO A-tile LDS — A fragments loaded straight from global
// (16B/lane spans, L1/L2-resident via XCD swizzle). Only Bs in LDS (17 KB)
// -> ~2.7x higher occupancy than v5. XCD-aware swizzled 1D grid as v5.
// Outputs: ct 0-3  -> qb8  fp8 [N][256]
//          ct 4-7  -> kvb  fp8 k-half:  node*512 + (c-256)
//          ct 8-11 -> kvb  fp8 v-half:  node*512 + 256 + (c-512)
//          ct 12   -> skipb bf16 [N][64]
// All epilogue stores are 64B-contiguous-per-row uint4 bursts via LDS tile.
// ---------------------------------------------------------------------------
template <int K>
__global__ __launch_bounds__(256) void gemm_v6(const ushort_t* __restrict__ A,
                                               const ushort_t* __restrict__ Wt,
                                               const float* __restrict__ bias,
                                               uchar_t* __restrict__ qb8,
                                               uchar_t* __restrict__ kvb,
                                               ushort_t* __restrict__ skipb,
                                               int N, int RB) {
    constexpr int KP = K + 8;      // padded LDS row stride (bf16 units)
    constexpr int C8 = K / 8;      // 16B chunks per row
    // max(Bs K=128: 64*136*2=17408, fp8 tile 128*80=10240, bf16 tile 128*68*2=17408)
    __shared__ uchar_t smem[17408] __attribute__((aligned(16)));
    ushort_t* Bs = (ushort_t*)smem;

    const int t = threadIdx.x;
    const int idx0 = blockIdx.x;
    const int xcd = idx0 & 7;
    const int j = idx0 >> 3;
    const int ct = j % 13;
    const int strip = (j / 13) * 8 + xcd;
    if (strip >= RB) return;
    const int base_r = strip * 128;
    const int base_c = ct * 64;

    // ---- stage B tile (64 cols of Wt) ----
#pragma unroll
    for (int i = 0; i < (64 * C8) / 256; ++i) {
        int ii = t + i * 256;
        int n = ii / C8, c = ii % C8;
        *(uint4*)(Bs + n * KP + c * 8) =
            *(const uint4*)(Wt + (size_t)(base_c + n) * K + c * 8);
    }

    const int wave = t >> 6, lane = t & 63;
    const int quad = lane >> 4, m16 = lane & 15;

    // ---- A fragments direct from global (clamped rows; OOB rows not stored) ----
    int arow0 = base_r + wave * 32 + m16;
    int arow1 = arow0 + 16;
    const ushort_t* Ar0 = A + (size_t)(arow0 < N ? arow0 : N - 1) * K + quad * 8;
    const ushort_t* Ar1 = A + (size_t)(arow1 < N ? arow1 : N - 1) * K + quad * 8;
    short8 a0[K / 32], a1[K / 32];
#pragma unroll
    for (int kc = 0; kc < K / 32; ++kc) {
        a0[kc] = *(const short8*)(Ar0 + kc * 32);
        a1[kc] = *(const short8*)(Ar1 + kc * 32);
    }
    __syncthreads();   // Bs ready

    floatx4 acc[2][4];
#pragma unroll
    for (int rt = 0; rt < 2; ++rt)
#pragma unroll
        for (int c2 = 0; c2 < 4; ++c2) acc[rt][c2] = (floatx4){0.f, 0.f, 0.f, 0.f};
#pragma unroll
    for (int kc = 0; kc < K / 32; ++kc) {
        int ko = kc * 32 + quad * 8;
#pragma unroll
        for (int c2 = 0; c2 < 4; ++c2) {
            short8 b = *(const short8*)(Bs + (c2 * 16 + m16) * KP + ko);
            acc[0][c2] = __builtin_amdgcn_mfma_f32_16x16x32_bf16(a0[kc], b, acc[0][c2], 0, 0, 0);
            acc[1][c2] = __builtin_amdgcn_mfma_f32_16x16x32_bf16(a1[kc], b, acc[1][c2], 0, 0, 0);
        }
    }

    // bias in-register
    float bb[4];
#pragma unroll
    for (int c2 = 0; c2 < 4; ++c2) bb[c2] = bias[base_c + c2 * 16 + m16];
#pragma unroll
    for (int rt = 0; rt < 2; ++rt)
#pragma unroll
        for (int c2 = 0; c2 < 4; ++c2)
#pragma unroll
            for (int r = 0; r < 4; ++r) acc[rt][c2][r] += bb[c2];

    __syncthreads();   // Bs free -> reuse for epilogue tile

    // lane element (rt,c2,r): row_l = wave*32+rt*16+quad*4+r, col_l = c2*16+m16
    if (ct < 12) {
        // fp8 tile [128][64] bytes, LDS stride 80 (non-pow2)
        uchar_t* ep = smem;
#pragma unroll
        for (int c2 = 0; c2 < 4; ++c2) {
            int col_l = c2 * 16 + m16;
#pragma unroll
            for (int rt = 0; rt < 2; ++rt)
#pragma unroll
                for (int r = 0; r < 4; ++r)
                    ep[(wave * 32 + rt * 16 + quad * 4 + r) * 80 + col_l] =
                        fp8e4m3(acc[rt][c2][r]);
        }
        __syncthreads();
        uchar_t* dstbase;
        size_t rstride;
        int off;
        if (ct < 4)      { dstbase = qb8; rstride = 256; off = base_c; }
        else if (ct < 8) { dstbase = kvb; rstride = 512; off = base_c - 256; }
        else             { dstbase = kvb; rstride = 512; off = 256 + (base_c - 512); }
#pragma unroll
        for (int i = 0; i < 2; ++i) {
            int ii = t + i * 256;
            int row = ii >> 2, ch = ii & 3;
            int gr = base_r + row;
            if (gr < N)
                *(uint4*)(dstbase + (size_t)gr * rstride + off + ch * 16) =
                    *(const uint4*)(ep + row * 80 + ch * 16);
        }
    } else {
        // skip tile: bf16 [128][64], LDS stride 68 ushorts
        ushort_t* ep = (ushort_t*)smem;
#pragma unroll
        for (int c2 = 0; c2 < 4; ++c2) {
            int col_l = c2 * 16 + m16;
#pragma unroll
            for (int rt = 0; rt < 2; ++rt)
#pragma unroll
                for (int r = 0; r < 4; ++r)
                    ep[(wave * 32 + rt * 16 + quad * 4 + r) * 68 + col_l] =
                        bf16rne(acc[rt][c2][r]);
        }
        __syncthreads();
#pragma unroll
        for (int i = 0; i < 4; ++i) {
            int ii = t + i * 256;
            int row = ii >> 3, ch = ii & 7;
            int gr = base_r + row;
            if (gr < N)
                *(uint4*)(skipb + (size_t)gr * 64 + ch * 8) =
                    *(const uint4*)(ep + row * 68 + ch * 8);
        }
    }
}

// ---------------------------------------------------------------------------
// TransformerConv aggregation v5: one wave per dst node, half-wave per edge.
// kvb layout: node*512 + [0:256)=k fp8, [256:512)=v fp8.
// sl = lane&31 owns dims [8*sl, 8*sl+8); head = sl>>3; dot-reduce shfl 1,2,4.
// ---------------------------------------------------------------------------
__device__ __forceinline__ void edge_step2(uint2 k8, uint2 v8, const float* qf,
                                           float& z, float* ac) {
    floatx2 k01 = __builtin_amdgcn_cvt_pk_f32_fp8(k8.x, false);
    floatx2 k23 = __builtin_amdgcn_cvt_pk_f32_fp8(k8.x, true);
    floatx2 k45 = __builtin_amdgcn_cvt_pk_f32_fp8(k8.y, false);
    floatx2 k67 = __builtin_amdgcn_cvt_pk_f32_fp8(k8.y, true);
    float d = qf[0] * k01[0] + qf[1] * k01[1] + qf[2] * k23[0] + qf[3] * k23[1]
            + qf[4] * k45[0] + qf[5] * k45[1] + qf[6] * k67[0] + qf[7] * k67[1];
    d += __shfl_xor(d, 1);
    d += __shfl_xor(d, 2);
    d += __shfl_xor(d, 4);
    float p = __expf(d * 0.125f);
    z += p;
    floatx2 v01 = __builtin_amdgcn_cvt_pk_f32_fp8(v8.x, false);
    floatx2 v23 = __builtin_amdgcn_cvt_pk_f32_fp8(v8.x, true);
    floatx2 v45 = __builtin_amdgcn_cvt_pk_f32_fp8(v8.y, false);
    floatx2 v67 = __builtin_amdgcn_cvt_pk_f32_fp8(v8.y, true);
    ac[0] = fmaf(p, v01[0], ac[0]); ac[1] = fmaf(p, v01[1], ac[1]);
    ac[2] = fmaf(p, v23[0], ac[2]); ac[3] = fmaf(p, v23[1], ac[3]);
    ac[4] = fmaf(p, v45[0], ac[4]); ac[5] = fmaf(p, v45[1], ac[5]);
    ac[6] = fmaf(p, v67[0], ac[6]); ac[7] = fmaf(p, v67[1], ac[7]);
}

template <bool OUT_BF16>
__global__ __launch_bounds__(256) void attn_agg5(const uchar_t* __restrict__ qb8,
                                                 const uchar_t* __restrict__ kvb,
                                                 const ushort_t* __restrict__ skipb,
                                                 const int* __restrict__ rowptr,
                                                 const int* __restrict__ col,
                                                 void* __restrict__ hout) {
    int node = blockIdx.x * 4 + threadIdx.y;
    if (node >= N_NODES) return;
    int lane = threadIdx.x;
    int half = lane >> 5, sl = lane & 31;
    uint2 qd = *(const uint2*)(qb8 + (size_t)node * 256 + sl * 8);
    floatx2 q01 = __builtin_amdgcn_cvt_pk_f32_fp8(qd.x, false);
    floatx2 q23 = __builtin_amdgcn_cvt_pk_f32_fp8(qd.x, true);
    floatx2 q45 = __builtin_amdgcn_cvt_pk_f32_fp8(qd.y, false);
    floatx2 q67 = __builtin_amdgcn_cvt_pk_f32_fp8(qd.y, true);
    float qf[8] = {q01[0], q01[1], q23[0], q23[1], q45[0], q45[1], q67[0], q67[1]};
    float ac[8] = {0.f, 0.f, 0.f, 0.f, 0.f, 0.f, 0.f, 0.f};
    float z = 0.f;
    int beg = rowptr[node], end = rowptr[node + 1];
    int e = beg + half;
    const size_t loff = (size_t)sl * 8;
    for (; e + 6 < end; e += 8) {
        const uchar_t* p0 = kvb + (size_t)col[e]     * 512 + loff;
        const uchar_t* p1 = kvb + (size_t)col[e + 2] * 512 + loff;
        const uchar_t* p2 = kvb + (size_t)col[e + 4] * 512 + loff;
        const uchar_t* p3 = kvb + (size_t)col[e + 6] * 512 + loff;
        uint2 k0 = *(const uint2*)p0, v0 = *(const uint2*)(p0 + 256);
        uint2 k1 = *(const uint2*)p1, v1 = *(const uint2*)(p1 + 256);
        uint2 k2 = *(const uint2*)p2, v2 = *(const uint2*)(p2 + 256);
        uint2 k3 = *(const uint2*)p3, v3 = *(const uint2*)(p3 + 256);
        edge_step2(k0, v0, qf, z, ac);
        edge_step2(k1, v1, qf, z, ac);
        edge_step2(k2, v2, qf, z, ac);
        edge_step2(k3, v3, qf, z, ac);
    }
    for (; e < end; e += 2) {
        const uchar_t* p0 = kvb + (size_t)col[e] * 512 + loff;
        uint2 k0 = *(const uint2*)p0, v0 = *(const uint2*)(p0 + 256);
        edge_step2(k0, v0, qf, z, ac);
    }
    z += __shfl_xor(z, 32);
#pragma unroll
    for (int i = 0; i < 8; ++i) ac[i] += __shfl_xor(ac[i], 32);
    float inv = (z > 0.f) ? (1.f / z) : 0.f;
#pragma unroll
    for (int i = 0; i < 8; ++i) ac[i] *= inv;
#pragma unroll
    for (int i = 0; i < 8; ++i) {
        ac[i] += __shfl_xor(ac[i], 8);
        ac[i] += __shfl_xor(ac[i], 16);
    }
    if (lane < 8) {   // lane holds output dims [8*lane, 8*lane+8)
        uint4 su = *(const uint4*)(skipb + (size_t)node * 64 + lane * 8);
        float4 s0 = bf4_unpack(su.x, su.y);
        float4 s1 = bf4_unpack(su.z, su.w);
        float o0 = fmaxf(ac[0] * 0.25f + s0.x, 0.f);
        float o1 = fmaxf(ac[1] * 0.25f + s0.y, 0.f);
        float o2 = fmaxf(ac[2] * 0.25f + s0.z, 0.f);
        float o3 = fmaxf(ac[3] * 0.25f + s0.w, 0.f);
        float o4 = fmaxf(ac[4] * 0.25f + s1.x, 0.f);
        float o5 = fmaxf(ac[5] * 0.25f + s1.y, 0.f);
        float o6 = fmaxf(ac[6] * 0.25f + s1.z, 0.f);
        float o7 = fmaxf(ac[7] * 0.25f + s1.w, 0.f);
        if (OUT_BF16) {
            uint4 u;
            u.x = (uint_t)bf16rne(o0) | ((uint_t)bf16rne(o1) << 16);
            u.y = (uint_t)bf16rne(o2) | ((uint_t)bf16rne(o3) << 16);
            u.z = (uint_t)bf16rne(o4) | ((uint_t)bf16rne(o5) << 16);
            u.w = (uint_t)bf16rne(o6) | ((uint_t)bf16rne(o7) << 16);
            *(uint4*)((ushort_t*)hout + (size_t)node * HIDDEN + lane * 8) = u;
        } else {
            float* op = (float*)hout + (size_t)node * HIDDEN + lane * 8;
            *(float4*)(op)     = make_float4(o0, o1, o2, o3);
            *(float4*)(op + 4) = make_float4(o4, o5, o6, o7);
        }
    }
}

// ---------------------------------------------------------------------------
// Per-graph mean pool (batch sorted -> binary search boundaries, no atomics)
// ---------------------------------------------------------------------------
__global__ void pool_mean(const float* __restrict__ h, const int* __restrict__ batch,
                          float* __restrict__ gsum, int* __restrict__ gcnt) {
    int g = blockIdx.x;
    int lo = 0, hi = N_NODES;
    while (lo < hi) { int mid = (lo + hi) >> 1; if (batch[mid] < g) lo = mid + 1; else hi = mid; }
    int start = lo;
    hi = N_NODES;
    while (lo < hi) { int mid = (lo + hi) >> 1; if (batch[mid] < g + 1) lo = mid + 1; else hi = mid; }
    int end = lo;
    int t = threadIdx.x;
    int d = t & 63, chunk = t >> 6;
    float acc = 0.f;
    for (int n = start + chunk; n < end; n += 4) acc += h[(size_t)n * HIDDEN + d];
    __shared__ float sh[256];
    sh[t] = acc;
    __syncthreads();
    if (chunk == 0) {
        gsum[g * HIDDEN + d] = sh[d] + sh[64 + d] + sh[128 + d] + sh[192 + d];
        if (d == 0) gcnt[g] = end - start;
    }
}

// ---------------------------------------------------------------------------
// Final MLP head: one block (64 threads) per graph
// ---------------------------------------------------------------------------
__global__ __launch_bounds__(64) void mlp_head(const float* __restrict__ gsum,
                                               const int* __restrict__ gcnt,
                                               const float* __restrict__ gf,
                                               const float* __restrict__ gW1, const float* __restrict__ gb1,
                                               const float* __restrict__ gW2, const float* __restrict__ gb2,
                                               const float* __restrict__ hW1, const float* __restrict__ hb1,
                                               const float* __restrict__ hW2, const float* __restrict__ hb2,
                                               float* __restrict__ out) {
    int g = blockIdx.x;
    int t = threadIdx.x;
    __shared__ float gfs[GLOBAL_DIM];
    __shared__ float g1[HIDDEN];
    __shared__ float fused[2 * HIDDEN];
    __shared__ float h1s[HIDDEN];
    for (int i = t; i < GLOBAL_DIM; i += 64) gfs[i] = gf[(size_t)g * GLOBAL_DIM + i];
    float cnt = (float)gcnt[g];
    cnt = fmaxf(cnt, 1.0f);
    fused[t] = gsum[g * HIDDEN + t] / cnt;
    __syncthreads();
    float acc = gb1[t];
    for (int k = 0; k < GLOBAL_DIM; ++k) acc = fmaf(gfs[k], gW1[k * HIDDEN + t], acc);
    g1[t] = fmaxf(acc, 0.f);
    __syncthreads();
    acc = gb2[t];
    for (int k = 0; k < HIDDEN; ++k) acc = fmaf(g1[k], gW2[k * HIDDEN + t], acc);
    fused[HIDDEN + t] = fmaxf(acc, 0.f);
    __syncthreads();
    acc = hb1[t];
    for (int k = 0; k < 2 * HIDDEN; ++k) acc = fmaf(fused[k], hW1[k * HIDDEN + t], acc);
    h1s[t] = fmaxf(acc, 0.f);
    __syncthreads();
    if (t < N_CLASSES) {
        float o = hb2[t];
        for (int k = 0; k < HIDDEN; ++k) o = fmaf(h1s[k], hW2[k * N_CLASSES + t], o);
        out[(size_t)g * N_CLASSES + t] = o;
    }
}

// ---------------------------------------------------------------------------
extern "C" void kernel_launch(void* const* d_in, const int* in_sizes, int n_in,
                              void* d_out, int out_size, void* d_ws, size_t ws_size,
                              hipStream_t stream) {
    const float* x        = (const float*)d_in[0];
    const int*   eidx     = (const int*)d_in[1];
    const int*   batch    = (const int*)d_in[2];
    const float* gfeats   = (const float*)d_in[3];
    const float* c1_Wq = (const float*)d_in[4];  const float* c1_bq = (const float*)d_in[5];
    const float* c1_Wk = (const float*)d_in[6];  const float* c1_bk = (const float*)d_in[7];
    const float* c1_Wv = (const float*)d_in[8];  const float* c1_bv = (const float*)d_in[9];
    const float* c1_Ws = (const float*)d_in[10]; const float* c1_bs = (const float*)d_in[11];
    const float* c2_Wq = (const float*)d_in[12]; const float* c2_bq = (const float*)d_in[13];
    const float* c2_Wk = (const float*)d_in[14]; const float* c2_bk = (const float*)d_in[15];
    const float* c2_Wv = (const float*)d_in[16]; const float* c2_bv = (const float*)d_in[17];
    const float* c2_Ws = (const float*)d_in[18]; const float* c2_bs = (const float*)d_in[19];
    const float* g_W1 = (const float*)d_in[20]; const float* g_b1 = (const float*)d_in[21];
    const float* g_W2 = (const float*)d_in[22]; const float* g_b2 = (const float*)d_in[23];
    const float* h_W1 = (const float*)d_in[24]; const float* h_b1 = (const float*)d_in[25];
    const float* h_W2 = (const float*)d_in[26]; const float* h_b2 = (const float*)d_in[27];
    float* out = (float*)d_out;

    const int* srcp = eidx;
    const int* dstp = eidx + N_EDGES;

    // ---- workspace layout ----
    char* base = (char*)d_ws;
    uchar_t*  kvb  = (uchar_t*)base;  base += (size_t)N_NODES * 512;         // 25.6 MB (k|v)
    uchar_t*  qb8  = (uchar_t*)base;  base += (size_t)N_NODES * 256;         // 12.8 MB
    ushort_t* skipb = (ushort_t*)base; base += (size_t)N_NODES * HIDDEN * 2; //  6.4 MB
    ushort_t* xb   = (ushort_t*)base; base += (size_t)N_NODES * IN_CH * 2;   // 12.8 MB
    ushort_t* h1b  = (ushort_t*)base; base += (size_t)N_NODES * HIDDEN * 2;  //  6.4 MB
    float*    h2   = (float*)base;    base += (size_t)N_NODES * HIDDEN * 4;  // 12.8 MB
    ushort_t* Wt1  = (ushort_t*)base; base += (size_t)IN_CH * QKV_COLS * 2;
    ushort_t* Wt2  = (ushort_t*)base; base += (size_t)HIDDEN * QKV_COLS * 2;
    float*    bcat1 = (float*)base;   base += QKV_COLS * 4;
    float*    bcat2 = (float*)base;   base += QKV_COLS * 4;
    float*    gsum = (float*)base;    base += N_GRAPHS * HIDDEN * 4;
    int* ib = (int*)base;
    size_t oi = 0;
    int* deg    = ib + oi; oi += N_NODES;
    int* incl   = ib + oi; oi += N_NODES;
    int* bsums  = ib + oi; oi += 64;
    int* rowptr = ib + oi; oi += N_NODES + 4;
    int* cur    = ib + oi; oi += N_NODES;
    int* colb   = ib + oi; oi += N_EDGES;
    int* gcnt   = ib + oi; oi += 64;

    const int NB1 = (N_NODES + 1023) / 1024;   // 49
    const int EB  = (N_EDGES + 255) / 256;     // 3125
    const int NBS = (N_NODES + 255) / 256;     // 196

    // ---- CSR build ----
    hipMemsetAsync(deg, 0, N_NODES * sizeof(int), stream);
    count_deg<<<782, 256, 0, stream>>>(dstp, deg);
    scan1<<<NB1, 1024, 0, stream>>>(deg, incl, bsums, N_NODES);
    scan3f<<<NBS, 256, 0, stream>>>(deg, incl, bsums, rowptr, cur, N_NODES);
    fill_col<<<EB, 256, 0, stream>>>(srcp, dstp, cur, colb);

    // ---- x -> bf16, weights ----
    cast_bf16_x8<<<(N_NODES * IN_CH / 8 + 255) / 256, 256, 0, stream>>>(x, xb, N_NODES * IN_CH / 8);
    const int CT = IN_CH * QKV_COLS + HIDDEN * QKV_COLS;
    concat_all<<<(CT + 255) / 256, 256, 0, stream>>>(
        c1_Wq, c1_Wk, c1_Wv, c1_Ws, c1_bq, c1_bk, c1_bv, c1_bs,
        c2_Wq, c2_Wk, c2_Wv, c2_Ws, c2_bq, c2_bk, c2_bv, c2_bs,
        Wt1, Wt2, bcat1, bcat2);

    const int RB = (N_NODES + 127) / 128;                  // 391
    const int GG = 8 * 13 * ((RB + 7) / 8);                // 5096
    dim3 attn_block(64, 4);
    int attn_grid = (N_NODES + 3) / 4;                     // 12500

    // ---- conv1 ----
    gemm_v6<IN_CH><<<GG, 256, 0, stream>>>(xb, Wt1, bcat1, qb8, kvb, skipb, N_NODES, RB);
    attn_agg5<true><<<attn_grid, attn_block, 0, stream>>>(qb8, kvb, skipb, rowptr, colb, h1b);

    // ---- conv2 ----
    gemm_v6<HIDDEN><<<GG, 256, 0, stream>>>(h1b, Wt2, bcat2, qb8, kvb, skipb, N_NODES, RB);
    attn_agg5<false><<<attn_grid, attn_block, 0, stream>>>(qb8, kvb, skipb, rowptr, colb, h2);

    // ---- pool + head ----
    pool_mean<<<N_GRAPHS, 256, 0, stream>>>(h2, batch, gsum, gcnt);
    mlp_head<<<N_GRAPHS, 64, 0, stream>>>(gsum, gcnt, gfeats,
                                          g_W1, g_b1, g_W2, g_b2,
                                          h_W1, h_b1, h_W2, h_b2, out);
}